// Round 6
// baseline (997.831 us; speedup 1.0000x reference)
//
#include <hip/hip_runtime.h>

#define NN 100000
#define EE 1600000
#define NBUCK ((NN + 255) >> 8)   // 391

typedef __attribute__((ext_vector_type(8))) short short8_t;
typedef __attribute__((ext_vector_type(4))) float f32x4;

static __device__ inline unsigned short f2bf(float f) {
    unsigned int u = __float_as_uint(f);
    u += 0x7FFFu + ((u >> 16) & 1u);
    return (unsigned short)(u >> 16);
}
static __device__ inline float bf2f(unsigned short h) {
    return __uint_as_float(((unsigned int)h) << 16);
}

// ================= CSR build (bucketed, low write-amplification) =================
__global__ void bucket_count(const int* __restrict__ ei, int* __restrict__ bcnt) {
    __shared__ int h[NBUCK];
    for (int i = threadIdx.x; i < NBUCK; i += 256) h[i] = 0;
    __syncthreads();
    for (int e = blockIdx.x * 256 + threadIdx.x; e < EE; e += gridDim.x * 256)
        atomicAdd(&h[ei[EE + e] >> 8], 1);
    __syncthreads();
    for (int i = threadIdx.x; i < NBUCK; i += 256) {
        int v = h[i];
        if (v) atomicAdd(&bcnt[i], v);
    }
}

__global__ void bucket_scan(const int* __restrict__ bcnt, int* __restrict__ bbase,
                            int* __restrict__ bcur) {
    __shared__ int s[512];
    int t = threadIdx.x;
    int v = (t < NBUCK) ? bcnt[t] : 0;
    s[t] = v;
    __syncthreads();
    for (int off = 1; off < 512; off <<= 1) {
        int u = (t >= off) ? s[t - off] : 0;
        __syncthreads();
        s[t] += u;
        __syncthreads();
    }
    int excl = s[t] - v;
    if (t < NBUCK) { bbase[t] = excl; bcur[t] = excl; }
    if (t == 0) bbase[NBUCK] = EE;
}

__global__ void bucket_append(const int* __restrict__ ei, int* __restrict__ bcur,
                              unsigned int* __restrict__ bbuf) {
    int e = blockIdx.x * 256 + threadIdx.x;
    if (e >= EE) return;
    int s = ei[e], d = ei[EE + e];
    int pos = atomicAdd(&bcur[d >> 8], 1);
    bbuf[pos] = (unsigned int)s | ((unsigned int)(d & 255) << 24);
}

__global__ __launch_bounds__(256) void csr_build(const unsigned int* __restrict__ bbuf,
                                                 const int* __restrict__ bbase,
                                                 int* __restrict__ row_ptr,
                                                 int* __restrict__ col) {
    __shared__ int hist[256];
    __shared__ int sc[256];
    __shared__ int lcur[256];
    int b = blockIdx.x;
    int t = threadIdx.x;
    int n0 = b << 8;
    int nCnt = NN - n0; if (nCnt > 256) nCnt = 256;
    int es = bbase[b], ee2 = bbase[b + 1];
    hist[t] = 0;
    __syncthreads();
    for (int i = es + t; i < ee2; i += 256)
        atomicAdd(&hist[bbuf[i] >> 24], 1);
    __syncthreads();
    int v = hist[t];
    sc[t] = v;
    __syncthreads();
    for (int off = 1; off < 256; off <<= 1) {
        int u = (t >= off) ? sc[t - off] : 0;
        __syncthreads();
        sc[t] += u;
        __syncthreads();
    }
    int excl = sc[t] - v;
    if (t < nCnt) row_ptr[n0 + t] = es + excl;
    if (b == 0 && t == 0) row_ptr[NN] = EE;
    lcur[t] = excl;
    __syncthreads();
    for (int i = es + t; i < ee2; i += 256) {
        unsigned int pk = bbuf[i];
        int lpos = atomicAdd(&lcur[pk >> 24], 1);
        col[es + lpos] = (int)(pk & 0x00FFFFFFu);
    }
}

// ================= small prep =================
__global__ void copy_logits_kernel(const float* __restrict__ logits, float* __restrict__ x) {
    int idx = blockIdx.x * blockDim.x + threadIdx.x;
    if (idx < NN * 10) {
        int n = idx / 10, q = idx - n * 10;
        *(float4*)(x + (long long)n * 168 + q * 4) = ((const float4*)logits)[idx];
    }
}

// W[K][N] f32 -> BT_hi/BT_lo[128][KP] bf16 (transposed, split, zero-padded)
__global__ void bsplit_kernel(const float* __restrict__ W, int K, int N,
                              unsigned short* __restrict__ BThi,
                              unsigned short* __restrict__ BTlo, int KP) {
    int k = blockIdx.x * 256 + threadIdx.x;
    int col = blockIdx.y;
    if (k >= KP) return;
    float v = (k < K && col < N) ? W[(size_t)k * N + col] : 0.f;
    unsigned short hi = f2bf(v);
    unsigned short lo = f2bf(v - bf2f(hi));
    BThi[(size_t)col * KP + k] = hi;
    BTlo[(size_t)col * KP + k] = lo;
}

// ================= split-bf16 MFMA GEMM: C[M,128] = A[M,K] @ B ===================
#define AHI 0
#define ALO 2048
#define BHI 4096
#define BLO 8192
template <int OUTBF16>
__global__ __launch_bounds__(256) void mfma_gemm_kernel(
    const float* __restrict__ A, int lda, int K, int M,
    const unsigned short* __restrict__ BThi, const unsigned short* __restrict__ BTlo, int KP,
    void* __restrict__ Cout, int ldc, int Nact, const float* __restrict__ bias)
{
    __shared__ __align__(16) unsigned short lds[12288];
    const int t = threadIdx.x;
    const int w = t >> 6, lane = t & 63;
    const int row0 = blockIdx.x * 64;
    const int rbase = (w & 1) * 32;
    const int cbase = (w >> 1) * 64;

    f32x4 acc[2][4];
#pragma unroll
    for (int i = 0; i < 2; ++i)
#pragma unroll
        for (int j = 0; j < 4; ++j) acc[i][j] = (f32x4){0.f, 0.f, 0.f, 0.f};

    const int arow = t >> 2;
    const int aslot = t & 3;
    const bool rowok = (row0 + arow) < M;
    const float* Arow = A + (size_t)(row0 + arow) * lda;
    const int aoff = arow * 32 + (((aslot ^ ((arow >> 1) & 3))) << 3);

    for (int k0 = 0; k0 < KP; k0 += 32) {
        {
            int gk = k0 + aslot * 8;
            float a[8];
            if (rowok && gk + 8 <= K) {
                float4 v0 = *(const float4*)(Arow + gk);
                float4 v1 = *(const float4*)(Arow + gk + 4);
                a[0] = v0.x; a[1] = v0.y; a[2] = v0.z; a[3] = v0.w;
                a[4] = v1.x; a[5] = v1.y; a[6] = v1.z; a[7] = v1.w;
            } else {
#pragma unroll
                for (int j = 0; j < 8; ++j) a[j] = 0.f;
            }
            short8_t vh, vl;
#pragma unroll
            for (int j = 0; j < 8; ++j) {
                unsigned short hi = f2bf(a[j]);
                vh[j] = (short)hi;
                vl[j] = (short)f2bf(a[j] - bf2f(hi));
            }
            *(short8_t*)&lds[AHI + aoff] = vh;
            *(short8_t*)&lds[ALO + aoff] = vl;
        }
#pragma unroll
        for (int i = 0; i < 2; ++i) {
            int idx = t + i * 256;
            int col = idx >> 2, slot = idx & 3;
            int bo = col * 32 + ((slot ^ ((col >> 1) & 3)) << 3);
            size_t gbo = (size_t)col * KP + k0 + slot * 8;
            *(short8_t*)&lds[BHI + bo] = *(const short8_t*)&BThi[gbo];
            *(short8_t*)&lds[BLO + bo] = *(const short8_t*)&BTlo[gbo];
        }
        __syncthreads();
        short8_t Ah[2], Al[2], Bh[4], Bl[4];
        const int fslot = lane >> 4;
#pragma unroll
        for (int rt = 0; rt < 2; ++rt) {
            int r = rbase + rt * 16 + (lane & 15);
            int off = r * 32 + ((fslot ^ ((r >> 1) & 3)) << 3);
            Ah[rt] = *(const short8_t*)&lds[AHI + off];
            Al[rt] = *(const short8_t*)&lds[ALO + off];
        }
#pragma unroll
        for (int ct = 0; ct < 4; ++ct) {
            int c = cbase + ct * 16 + (lane & 15);
            int off = c * 32 + ((fslot ^ ((c >> 1) & 3)) << 3);
            Bh[ct] = *(const short8_t*)&lds[BHI + off];
            Bl[ct] = *(const short8_t*)&lds[BLO + off];
        }
#pragma unroll
        for (int rt = 0; rt < 2; ++rt)
#pragma unroll
            for (int ct = 0; ct < 4; ++ct) {
                acc[rt][ct] = __builtin_amdgcn_mfma_f32_16x16x32_bf16(Ah[rt], Bh[ct], acc[rt][ct], 0, 0, 0);
                acc[rt][ct] = __builtin_amdgcn_mfma_f32_16x16x32_bf16(Ah[rt], Bl[ct], acc[rt][ct], 0, 0, 0);
                acc[rt][ct] = __builtin_amdgcn_mfma_f32_16x16x32_bf16(Al[rt], Bh[ct], acc[rt][ct], 0, 0, 0);
            }
        __syncthreads();
    }

#pragma unroll
    for (int rt = 0; rt < 2; ++rt) {
#pragma unroll
        for (int reg = 0; reg < 4; ++reg) {
            int r = row0 + rbase + rt * 16 + (lane >> 4) * 4 + reg;
            if (r >= M) continue;
#pragma unroll
            for (int ct = 0; ct < 4; ++ct) {
                int c = cbase + ct * 16 + (lane & 15);
                float v = acc[rt][ct][reg];
                if (OUTBF16) {
                    ((unsigned short*)Cout)[(size_t)r * 128 + c] = f2bf(v);
                } else {
                    if (c < Nact)
                        ((float*)Cout)[(size_t)r * ldc + c] = v + (bias ? bias[c] : 0.f);
                }
            }
        }
    }
}

// ================= attention coefficients from bf16 h =================
__global__ void attn_coef_bf16(const unsigned short* __restrict__ hb,
                               const float* __restrict__ att_src,
                               const float* __restrict__ att_dst,
                               float* __restrict__ a_src, float* __restrict__ a_dst) {
    int n = (blockIdx.x * 256 + threadIdx.x) >> 6;
    if (n >= NN) return;
    int lane = threadIdx.x & 63;
    unsigned int hv = ((const unsigned int*)hb)[n * 64 + lane];
    float hx = __uint_as_float(hv << 16);
    float hy = __uint_as_float(hv & 0xFFFF0000u);
    int c0 = lane * 2;
    float vs = hx * att_src[c0] + hy * att_src[c0 + 1];
    float vd = hx * att_dst[c0] + hy * att_dst[c0 + 1];
#pragma unroll
    for (int off = 1; off <= 16; off <<= 1) {
        vs += __shfl_xor(vs, off);
        vd += __shfl_xor(vd, off);
    }
    if ((lane & 31) == 0) {
        int head = lane >> 5;
        a_src[n * 2 + head] = vs;
        a_dst[n * 2 + head] = vd;
    }
}

// ================= fused GAT aggregation (CSR gather + inline weights) ============
// one wave per node; lane owns channels {2*lane, 2*lane+1}; head = lane>>5.
// Weights computed batch-64: lane L computes both heads' w for edge base+L, then
// broadcast via shuffles during the channel loop.
template <int RELU>
__global__ void gat_agg_fused(const int* __restrict__ row_ptr, const int* __restrict__ col,
                              const float* __restrict__ a_src, const float* __restrict__ a_dst,
                              const unsigned short* __restrict__ hb,
                              const float* __restrict__ bias, float* __restrict__ out) {
    int wid = (blockIdx.x * 256 + threadIdx.x) >> 6;
    if (wid >= NN) return;
    int lane = threadIdx.x & 63;
    int head = lane >> 5;
    const unsigned int* h2 = (const unsigned int*)hb;

    float2 ad = ((const float2*)a_dst)[wid];
    float2 asf = ((const float2*)a_src)[wid];
    float e0 = (head ? asf.y : asf.x) + (head ? ad.y : ad.x);
    e0 = e0 > 0.f ? e0 : 0.2f * e0;
    float w = __expf(e0);
    unsigned int hv = h2[wid * 64 + lane];
    float accx = w * __uint_as_float(hv << 16);
    float accy = w * __uint_as_float(hv & 0xFFFF0000u);
    float den = w;

    int rs = row_ptr[wid], re = row_ptr[wid + 1];
    for (int base = rs; base < re; base += 64) {
        int cnt = re - base;
        if (cnt > 64) cnt = 64;
        int sL = 0;
        float w0 = 0.f, w1 = 0.f;
        if (lane < cnt) {
            sL = col[base + lane];
            float2 as = ((const float2*)a_src)[sL];
            float t0 = as.x + ad.x;
            float t1 = as.y + ad.y;
            t0 = t0 > 0.f ? t0 : 0.2f * t0;
            t1 = t1 > 0.f ? t1 : 0.2f * t1;
            w0 = __expf(t0);
            w1 = __expf(t1);
        }
        for (int i = 0; i < cnt; ++i) {
            int s = __shfl(sL, i);
            float wa = __shfl(w0, i);
            float wb = __shfl(w1, i);
            float ws = head ? wb : wa;
            unsigned int hs = h2[s * 64 + lane];
            accx += ws * __uint_as_float(hs << 16);
            accy += ws * __uint_as_float(hs & 0xFFFF0000u);
            den += ws;
        }
    }
    float inv = 1.f / (den + 1e-16f);
    float2 b2 = ((const float2*)bias)[lane];
    float ox = accx * inv + b2.x;
    float oy = accy * inv + b2.y;
    if (RELU) { ox = fmaxf(ox, 0.f); oy = fmaxf(oy, 0.f); }
    ((float2*)out)[wid * 64 + lane] = make_float2(ox, oy);
}

extern "C" void kernel_launch(void* const* d_in, const int* in_sizes, int n_in,
                              void* d_out, int out_size, void* d_ws, size_t ws_size,
                              hipStream_t stream) {
    const float* logits   = (const float*)d_in[0];
    const float* features = (const float*)d_in[1];
    const int*   ei       = (const int*)d_in[2];
    const float* W_feat   = (const float*)d_in[3];
    const float* b_feat   = (const float*)d_in[4];
    const float* W0       = (const float*)d_in[5];
    const float* att_src0 = (const float*)d_in[6];
    const float* att_dst0 = (const float*)d_in[7];
    const float* bias0    = (const float*)d_in[8];
    const float* W1       = (const float*)d_in[9];
    const float* att_src1 = (const float*)d_in[10];
    const float* att_dst1 = (const float*)d_in[11];
    const float* bias1    = (const float*)d_in[12];
    const float* W_out    = (const float*)d_in[13];
    const float* b_out    = (const float*)d_in[14];
    float* out = (float*)d_out;

    float* x0     = (float*)d_ws;                       // NN*168
    float* agg    = x0 + (size_t)NN * 168;              // NN*128
    float* a_srcb = agg + (size_t)NN * 128;             // NN*2
    float* a_dstb = a_srcb + (size_t)NN * 2;            // NN*2
    unsigned short* hbuf = (unsigned short*)(a_dstb + (size_t)NN * 2); // NN*128 bf16
    unsigned short* BThi_f = hbuf + (size_t)NN * 128;   // 128*256
    unsigned short* BTlo_f = BThi_f + 128 * 256;
    unsigned short* BThi_0 = BTlo_f + 128 * 256;        // 128*192
    unsigned short* BTlo_0 = BThi_0 + 128 * 192;
    unsigned short* BThi_1 = BTlo_0 + 128 * 192;        // 128*128
    unsigned short* BTlo_1 = BThi_1 + 128 * 128;
    unsigned short* BThi_o = BTlo_1 + 128 * 128;        // 128*128
    unsigned short* BTlo_o = BThi_o + 128 * 128;
    int* row_ptr = (int*)(BTlo_o + 128 * 128);          // NN+1
    int* colbuf  = row_ptr + NN + 1;                    // EE
    int* bcnt    = colbuf + EE;                         // NBUCK
    int* bbase   = bcnt + NBUCK;                        // NBUCK+1
    int* bcur    = bbase + NBUCK + 1;                   // NBUCK
    unsigned int* bbuf = (unsigned int*)agg;            // EE u32, aliases agg (dead until L0 agg)

    dim3 blk(256);
    const int gemmGrid = (NN + 63) / 64;
    const int nodeWaveGrid = (NN + 3) / 4;

    // ---- CSR build (bucketed) ----
    hipMemsetAsync(bcnt, 0, (size_t)NBUCK * sizeof(int), stream);
    bucket_count<<<dim3(512), blk, 0, stream>>>(ei, bcnt);
    bucket_scan<<<dim3(1), dim3(512), 0, stream>>>(bcnt, bbase, bcur);
    bucket_append<<<dim3((EE + 255) / 256), blk, 0, stream>>>(ei, bcur, bbuf);
    csr_build<<<dim3(NBUCK), blk, 0, stream>>>(bbuf, bbase, row_ptr, colbuf);

    // ---- split/transpose weights ----
    bsplit_kernel<<<dim3(1, 128), blk, 0, stream>>>(W_feat, 256, 128, BThi_f, BTlo_f, 256);
    bsplit_kernel<<<dim3(1, 128), blk, 0, stream>>>(W0, 168, 128, BThi_0, BTlo_0, 192);
    bsplit_kernel<<<dim3(1, 128), blk, 0, stream>>>(W1, 128, 128, BThi_1, BTlo_1, 128);
    bsplit_kernel<<<dim3(1, 128), blk, 0, stream>>>(W_out, 128, 40, BThi_o, BTlo_o, 128);

    // ---- input assembly ----
    copy_logits_kernel<<<dim3((NN * 10 + 255) / 256), blk, 0, stream>>>(logits, x0);
    mfma_gemm_kernel<0><<<dim3(gemmGrid), blk, 0, stream>>>(
        features, 256, 256, NN, BThi_f, BTlo_f, 256, x0 + 40, 168, 128, b_feat);

    // ---- GAT layer 0 ----
    mfma_gemm_kernel<1><<<dim3(gemmGrid), blk, 0, stream>>>(
        x0, 168, 168, NN, BThi_0, BTlo_0, 192, hbuf, 128, 128, nullptr);
    attn_coef_bf16<<<dim3(nodeWaveGrid), blk, 0, stream>>>(hbuf, att_src0, att_dst0, a_srcb, a_dstb);
    // bbuf (aliasing agg) dead from here; agg becomes live
    gat_agg_fused<1><<<dim3(nodeWaveGrid), blk, 0, stream>>>(
        row_ptr, colbuf, a_srcb, a_dstb, hbuf, bias0, agg);

    // ---- GAT layer 1 ----
    mfma_gemm_kernel<1><<<dim3(gemmGrid), blk, 0, stream>>>(
        agg, 128, 128, NN, BThi_1, BTlo_1, 128, hbuf, 128, 128, nullptr);
    attn_coef_bf16<<<dim3(nodeWaveGrid), blk, 0, stream>>>(hbuf, att_src1, att_dst1, a_srcb, a_dstb);
    gat_agg_fused<0><<<dim3(nodeWaveGrid), blk, 0, stream>>>(
        row_ptr, colbuf, a_srcb, a_dstb, hbuf, bias1, agg);

    // ---- output projection ----
    mfma_gemm_kernel<0><<<dim3(gemmGrid), blk, 0, stream>>>(
        agg, 128, 128, NN, BThi_o, BTlo_o, 128, out, 40, 40, b_out);
}

// Round 7
// 468.920 us; speedup vs baseline: 2.1279x; 2.1279x over previous
//
#include <hip/hip_runtime.h>

#define NN 100000
#define EE 1600000
#define NBUCK ((NN + 255) >> 8)        // 391
#define CHUNK 8192
#define NPBLK ((EE + CHUNK - 1) / CHUNK) // 196

typedef __attribute__((ext_vector_type(8))) short short8_t;
typedef __attribute__((ext_vector_type(4))) float f32x4;

static __device__ inline unsigned short f2bf(float f) {
    unsigned int u = __float_as_uint(f);
    u += 0x7FFFu + ((u >> 16) & 1u);
    return (unsigned short)(u >> 16);
}
static __device__ inline float bf2f(unsigned short h) {
    return __uint_as_float(((unsigned int)h) << 16);
}

// ================= CSR build: contention-free radix partition =================
__global__ __launch_bounds__(256) void part_count(const int* __restrict__ ei,
                                                  int* __restrict__ cnt) {
    __shared__ int h[NBUCK];
    for (int i = threadIdx.x; i < NBUCK; i += 256) h[i] = 0;
    __syncthreads();
    int e0 = blockIdx.x * CHUNK;
    int e1 = e0 + CHUNK; if (e1 > EE) e1 = EE;
    for (int e = e0 + threadIdx.x; e < e1; e += 256)
        atomicAdd(&h[ei[EE + e] >> 8], 1);
    __syncthreads();
    for (int i = threadIdx.x; i < NBUCK; i += 256)
        cnt[blockIdx.x * NBUCK + i] = h[i];
}

__global__ void part_scan(const int* __restrict__ cnt, int* __restrict__ base,
                          int* __restrict__ bbase) {
    __shared__ int tot[512];
    int b = threadIdx.x;
    int t = 0;
    if (b < NBUCK)
        for (int k = 0; k < NPBLK; ++k) t += cnt[k * NBUCK + b];
    tot[b] = t;
    __syncthreads();
    for (int off = 1; off < 512; off <<= 1) {
        int u = (b >= off) ? tot[b - off] : 0;
        __syncthreads();
        tot[b] += u;
        __syncthreads();
    }
    int excl = tot[b] - t;
    if (b < NBUCK) {
        bbase[b] = excl;
        int run = excl;
        for (int k = 0; k < NPBLK; ++k) {
            base[k * NBUCK + b] = run;
            run += cnt[k * NBUCK + b];
        }
    }
    if (b == 0) bbase[NBUCK] = EE;
}

__global__ __launch_bounds__(256) void part_scatter(const int* __restrict__ ei,
                                                    const int* __restrict__ base,
                                                    unsigned int* __restrict__ bbuf) {
    __shared__ int lcur[NBUCK];
    for (int i = threadIdx.x; i < NBUCK; i += 256)
        lcur[i] = base[blockIdx.x * NBUCK + i];
    __syncthreads();
    int e0 = blockIdx.x * CHUNK;
    int e1 = e0 + CHUNK; if (e1 > EE) e1 = EE;
    for (int e = e0 + threadIdx.x; e < e1; e += 256) {
        int s = ei[e], d = ei[EE + e];
        int pos = atomicAdd(&lcur[d >> 8], 1);
        bbuf[pos] = (unsigned int)s | ((unsigned int)(d & 255) << 24);
    }
}

__global__ __launch_bounds__(256) void csr_build(const unsigned int* __restrict__ bbuf,
                                                 const int* __restrict__ bbase,
                                                 int* __restrict__ row_ptr,
                                                 int* __restrict__ col) {
    __shared__ int hist[256];
    __shared__ int sc[256];
    __shared__ int lcur[256];
    int b = blockIdx.x;
    int t = threadIdx.x;
    int n0 = b << 8;
    int nCnt = NN - n0; if (nCnt > 256) nCnt = 256;
    int es = bbase[b], ee2 = bbase[b + 1];
    hist[t] = 0;
    __syncthreads();
    for (int i = es + t; i < ee2; i += 256)
        atomicAdd(&hist[bbuf[i] >> 24], 1);
    __syncthreads();
    int v = hist[t];
    sc[t] = v;
    __syncthreads();
    for (int off = 1; off < 256; off <<= 1) {
        int u = (t >= off) ? sc[t - off] : 0;
        __syncthreads();
        sc[t] += u;
        __syncthreads();
    }
    int excl = sc[t] - v;
    if (t < nCnt) row_ptr[n0 + t] = es + excl;
    if (b == 0 && t == 0) row_ptr[NN] = EE;
    lcur[t] = excl;
    __syncthreads();
    for (int i = es + t; i < ee2; i += 256) {
        unsigned int pk = bbuf[i];
        int lpos = atomicAdd(&lcur[pk >> 24], 1);
        col[es + lpos] = (int)(pk & 0x00FFFFFFu);
    }
}

// ================= small prep =================
__global__ void copy_logits_kernel(const float* __restrict__ logits, float* __restrict__ x) {
    int idx = blockIdx.x * blockDim.x + threadIdx.x;
    if (idx < NN * 10) {
        int n = idx / 10, q = idx - n * 10;
        *(float4*)(x + (long long)n * 168 + q * 4) = ((const float4*)logits)[idx];
    }
}

// W[K][N] f32 -> BT_hi/BT_lo[128][KP] bf16 (transposed, split, zero-padded)
__global__ void bsplit_kernel(const float* __restrict__ W, int K, int N,
                              unsigned short* __restrict__ BThi,
                              unsigned short* __restrict__ BTlo, int KP) {
    int k = blockIdx.x * 256 + threadIdx.x;
    int col = blockIdx.y;
    if (k >= KP) return;
    float v = (k < K && col < N) ? W[(size_t)k * N + col] : 0.f;
    unsigned short hi = f2bf(v);
    unsigned short lo = f2bf(v - bf2f(hi));
    BThi[(size_t)col * KP + k] = hi;
    BTlo[(size_t)col * KP + k] = lo;
}

// ================= split-bf16 MFMA GEMM: C[M,128] = A[M,K] @ B ===================
#define AHI 0
#define ALO 2048
#define BHI 4096
#define BLO 8192
template <int OUTBF16>
__global__ __launch_bounds__(256) void mfma_gemm_kernel(
    const float* __restrict__ A, int lda, int K, int M,
    const unsigned short* __restrict__ BThi, const unsigned short* __restrict__ BTlo, int KP,
    void* __restrict__ Cout, int ldc, int Nact, const float* __restrict__ bias)
{
    __shared__ __align__(16) unsigned short lds[12288];
    const int t = threadIdx.x;
    const int w = t >> 6, lane = t & 63;
    const int row0 = blockIdx.x * 64;
    const int rbase = (w & 1) * 32;
    const int cbase = (w >> 1) * 64;

    f32x4 acc[2][4];
#pragma unroll
    for (int i = 0; i < 2; ++i)
#pragma unroll
        for (int j = 0; j < 4; ++j) acc[i][j] = (f32x4){0.f, 0.f, 0.f, 0.f};

    const int arow = t >> 2;
    const int aslot = t & 3;
    const bool rowok = (row0 + arow) < M;
    const float* Arow = A + (size_t)(row0 + arow) * lda;
    const int aoff = arow * 32 + (((aslot ^ ((arow >> 1) & 3))) << 3);

    for (int k0 = 0; k0 < KP; k0 += 32) {
        {
            int gk = k0 + aslot * 8;
            float a[8];
            if (rowok && gk + 8 <= K) {
                float4 v0 = *(const float4*)(Arow + gk);
                float4 v1 = *(const float4*)(Arow + gk + 4);
                a[0] = v0.x; a[1] = v0.y; a[2] = v0.z; a[3] = v0.w;
                a[4] = v1.x; a[5] = v1.y; a[6] = v1.z; a[7] = v1.w;
            } else {
#pragma unroll
                for (int j = 0; j < 8; ++j) a[j] = 0.f;
            }
            short8_t vh, vl;
#pragma unroll
            for (int j = 0; j < 8; ++j) {
                unsigned short hi = f2bf(a[j]);
                vh[j] = (short)hi;
                vl[j] = (short)f2bf(a[j] - bf2f(hi));
            }
            *(short8_t*)&lds[AHI + aoff] = vh;
            *(short8_t*)&lds[ALO + aoff] = vl;
        }
#pragma unroll
        for (int i = 0; i < 2; ++i) {
            int idx = t + i * 256;
            int col = idx >> 2, slot = idx & 3;
            int bo = col * 32 + ((slot ^ ((col >> 1) & 3)) << 3);
            size_t gbo = (size_t)col * KP + k0 + slot * 8;
            *(short8_t*)&lds[BHI + bo] = *(const short8_t*)&BThi[gbo];
            *(short8_t*)&lds[BLO + bo] = *(const short8_t*)&BTlo[gbo];
        }
        __syncthreads();
        short8_t Ah[2], Al[2], Bh[4], Bl[4];
        const int fslot = lane >> 4;
#pragma unroll
        for (int rt = 0; rt < 2; ++rt) {
            int r = rbase + rt * 16 + (lane & 15);
            int off = r * 32 + ((fslot ^ ((r >> 1) & 3)) << 3);
            Ah[rt] = *(const short8_t*)&lds[AHI + off];
            Al[rt] = *(const short8_t*)&lds[ALO + off];
        }
#pragma unroll
        for (int ct = 0; ct < 4; ++ct) {
            int c = cbase + ct * 16 + (lane & 15);
            int off = c * 32 + ((fslot ^ ((c >> 1) & 3)) << 3);
            Bh[ct] = *(const short8_t*)&lds[BHI + off];
            Bl[ct] = *(const short8_t*)&lds[BLO + off];
        }
#pragma unroll
        for (int rt = 0; rt < 2; ++rt)
#pragma unroll
            for (int ct = 0; ct < 4; ++ct) {
                acc[rt][ct] = __builtin_amdgcn_mfma_f32_16x16x32_bf16(Ah[rt], Bh[ct], acc[rt][ct], 0, 0, 0);
                acc[rt][ct] = __builtin_amdgcn_mfma_f32_16x16x32_bf16(Ah[rt], Bl[ct], acc[rt][ct], 0, 0, 0);
                acc[rt][ct] = __builtin_amdgcn_mfma_f32_16x16x32_bf16(Al[rt], Bh[ct], acc[rt][ct], 0, 0, 0);
            }
        __syncthreads();
    }

#pragma unroll
    for (int rt = 0; rt < 2; ++rt) {
#pragma unroll
        for (int reg = 0; reg < 4; ++reg) {
            int r = row0 + rbase + rt * 16 + (lane >> 4) * 4 + reg;
            if (r >= M) continue;
#pragma unroll
            for (int ct = 0; ct < 4; ++ct) {
                int c = cbase + ct * 16 + (lane & 15);
                float v = acc[rt][ct][reg];
                if (OUTBF16) {
                    ((unsigned short*)Cout)[(size_t)r * 128 + c] = f2bf(v);
                } else {
                    if (c < Nact)
                        ((float*)Cout)[(size_t)r * ldc + c] = v + (bias ? bias[c] : 0.f);
                }
            }
        }
    }
}

// ================= attention coefficients from bf16 h =================
__global__ void attn_coef_bf16(const unsigned short* __restrict__ hb,
                               const float* __restrict__ att_src,
                               const float* __restrict__ att_dst,
                               float* __restrict__ a_src, float* __restrict__ a_dst) {
    int n = (blockIdx.x * 256 + threadIdx.x) >> 6;
    if (n >= NN) return;
    int lane = threadIdx.x & 63;
    unsigned int hv = ((const unsigned int*)hb)[n * 64 + lane];
    float hx = __uint_as_float(hv << 16);
    float hy = __uint_as_float(hv & 0xFFFF0000u);
    int c0 = lane * 2;
    float vs = hx * att_src[c0] + hy * att_src[c0 + 1];
    float vd = hx * att_dst[c0] + hy * att_dst[c0 + 1];
#pragma unroll
    for (int off = 1; off <= 16; off <<= 1) {
        vs += __shfl_xor(vs, off);
        vd += __shfl_xor(vd, off);
    }
    if ((lane & 31) == 0) {
        int head = lane >> 5;
        a_src[n * 2 + head] = vs;
        a_dst[n * 2 + head] = vd;
    }
}

// ================= fused GAT aggregation (CSR gather + inline weights) ============
template <int RELU>
__global__ void gat_agg_fused(const int* __restrict__ row_ptr, const int* __restrict__ col,
                              const float* __restrict__ a_src, const float* __restrict__ a_dst,
                              const unsigned short* __restrict__ hb,
                              const float* __restrict__ bias, float* __restrict__ out) {
    int wid = (blockIdx.x * 256 + threadIdx.x) >> 6;
    if (wid >= NN) return;
    int lane = threadIdx.x & 63;
    int head = lane >> 5;
    const unsigned int* h2 = (const unsigned int*)hb;

    float2 ad = ((const float2*)a_dst)[wid];
    float2 asf = ((const float2*)a_src)[wid];
    float e0 = (head ? asf.y : asf.x) + (head ? ad.y : ad.x);
    e0 = e0 > 0.f ? e0 : 0.2f * e0;
    float w = __expf(e0);
    unsigned int hv = h2[wid * 64 + lane];
    float accx = w * __uint_as_float(hv << 16);
    float accy = w * __uint_as_float(hv & 0xFFFF0000u);
    float den = w;

    int rs = row_ptr[wid], re = row_ptr[wid + 1];
    for (int base = rs; base < re; base += 64) {
        int cnt = re - base;
        if (cnt > 64) cnt = 64;
        int sL = 0;
        float w0 = 0.f, w1 = 0.f;
        if (lane < cnt) {
            sL = col[base + lane];
            float2 as = ((const float2*)a_src)[sL];
            float t0 = as.x + ad.x;
            float t1 = as.y + ad.y;
            t0 = t0 > 0.f ? t0 : 0.2f * t0;
            t1 = t1 > 0.f ? t1 : 0.2f * t1;
            w0 = __expf(t0);
            w1 = __expf(t1);
        }
        for (int i = 0; i < cnt; ++i) {
            int s = __shfl(sL, i);
            float wa = __shfl(w0, i);
            float wb = __shfl(w1, i);
            float ws = head ? wb : wa;
            unsigned int hs = h2[s * 64 + lane];
            accx += ws * __uint_as_float(hs << 16);
            accy += ws * __uint_as_float(hs & 0xFFFF0000u);
            den += ws;
        }
    }
    float inv = 1.f / (den + 1e-16f);
    float2 b2 = ((const float2*)bias)[lane];
    float ox = accx * inv + b2.x;
    float oy = accy * inv + b2.y;
    if (RELU) { ox = fmaxf(ox, 0.f); oy = fmaxf(oy, 0.f); }
    ((float2*)out)[wid * 64 + lane] = make_float2(ox, oy);
}

extern "C" void kernel_launch(void* const* d_in, const int* in_sizes, int n_in,
                              void* d_out, int out_size, void* d_ws, size_t ws_size,
                              hipStream_t stream) {
    const float* logits   = (const float*)d_in[0];
    const float* features = (const float*)d_in[1];
    const int*   ei       = (const int*)d_in[2];
    const float* W_feat   = (const float*)d_in[3];
    const float* b_feat   = (const float*)d_in[4];
    const float* W0       = (const float*)d_in[5];
    const float* att_src0 = (const float*)d_in[6];
    const float* att_dst0 = (const float*)d_in[7];
    const float* bias0    = (const float*)d_in[8];
    const float* W1       = (const float*)d_in[9];
    const float* att_src1 = (const float*)d_in[10];
    const float* att_dst1 = (const float*)d_in[11];
    const float* bias1    = (const float*)d_in[12];
    const float* W_out    = (const float*)d_in[13];
    const float* b_out    = (const float*)d_in[14];
    float* out = (float*)d_out;

    float* x0     = (float*)d_ws;                       // NN*168
    float* agg    = x0 + (size_t)NN * 168;              // NN*128
    float* a_srcb = agg + (size_t)NN * 128;             // NN*2
    float* a_dstb = a_srcb + (size_t)NN * 2;            // NN*2
    unsigned short* hbuf = (unsigned short*)(a_dstb + (size_t)NN * 2); // NN*128 bf16
    unsigned short* BThi_f = hbuf + (size_t)NN * 128;   // 128*256
    unsigned short* BTlo_f = BThi_f + 128 * 256;
    unsigned short* BThi_0 = BTlo_f + 128 * 256;        // 128*192
    unsigned short* BTlo_0 = BThi_0 + 128 * 192;
    unsigned short* BThi_1 = BTlo_0 + 128 * 192;        // 128*128
    unsigned short* BTlo_1 = BThi_1 + 128 * 128;
    unsigned short* BThi_o = BTlo_1 + 128 * 128;        // 128*128
    unsigned short* BTlo_o = BThi_o + 128 * 128;
    int* row_ptr = (int*)(BTlo_o + 128 * 128);          // NN+1
    int* colbuf  = row_ptr + NN + 1;                    // EE
    int* cnt     = colbuf + EE;                         // NPBLK*NBUCK
    int* pbase   = cnt + NPBLK * NBUCK;                 // NPBLK*NBUCK
    int* bbase   = pbase + NPBLK * NBUCK;               // NBUCK+1
    unsigned int* bbuf = (unsigned int*)agg;            // EE u32, aliases agg (dead until L0 agg)

    dim3 blk(256);
    const int gemmGrid = (NN + 63) / 64;
    const int nodeWaveGrid = (NN + 3) / 4;

    // ---- CSR build (contention-free radix partition) ----
    part_count<<<dim3(NPBLK), blk, 0, stream>>>(ei, cnt);
    part_scan<<<dim3(1), dim3(512), 0, stream>>>(cnt, pbase, bbase);
    part_scatter<<<dim3(NPBLK), blk, 0, stream>>>(ei, pbase, bbuf);
    csr_build<<<dim3(NBUCK), blk, 0, stream>>>(bbuf, bbase, row_ptr, colbuf);

    // ---- split/transpose weights ----
    bsplit_kernel<<<dim3(1, 128), blk, 0, stream>>>(W_feat, 256, 128, BThi_f, BTlo_f, 256);
    bsplit_kernel<<<dim3(1, 128), blk, 0, stream>>>(W0, 168, 128, BThi_0, BTlo_0, 192);
    bsplit_kernel<<<dim3(1, 128), blk, 0, stream>>>(W1, 128, 128, BThi_1, BTlo_1, 128);
    bsplit_kernel<<<dim3(1, 128), blk, 0, stream>>>(W_out, 128, 40, BThi_o, BTlo_o, 128);

    // ---- input assembly ----
    copy_logits_kernel<<<dim3((NN * 10 + 255) / 256), blk, 0, stream>>>(logits, x0);
    mfma_gemm_kernel<0><<<dim3(gemmGrid), blk, 0, stream>>>(
        features, 256, 256, NN, BThi_f, BTlo_f, 256, x0 + 40, 168, 128, b_feat);

    // ---- GAT layer 0 ----
    mfma_gemm_kernel<1><<<dim3(gemmGrid), blk, 0, stream>>>(
        x0, 168, 168, NN, BThi_0, BTlo_0, 192, hbuf, 128, 128, nullptr);
    attn_coef_bf16<<<dim3(nodeWaveGrid), blk, 0, stream>>>(hbuf, att_src0, att_dst0, a_srcb, a_dstb);
    // bbuf (aliasing agg) dead from here; agg becomes live
    gat_agg_fused<1><<<dim3(nodeWaveGrid), blk, 0, stream>>>(
        row_ptr, colbuf, a_srcb, a_dstb, hbuf, bias0, agg);

    // ---- GAT layer 1 ----
    mfma_gemm_kernel<1><<<dim3(gemmGrid), blk, 0, stream>>>(
        agg, 128, 128, NN, BThi_1, BTlo_1, 128, hbuf, 128, 128, nullptr);
    attn_coef_bf16<<<dim3(nodeWaveGrid), blk, 0, stream>>>(hbuf, att_src1, att_dst1, a_srcb, a_dstb);
    gat_agg_fused<0><<<dim3(nodeWaveGrid), blk, 0, stream>>>(
        row_ptr, colbuf, a_srcb, a_dstb, hbuf, bias1, agg);

    // ---- output projection ----
    mfma_gemm_kernel<0><<<dim3(gemmGrid), blk, 0, stream>>>(
        agg, 128, 128, NN, BThi_o, BTlo_o, 128, out, 40, 40, b_out);
}

// Round 8
// 347.866 us; speedup vs baseline: 2.8684x; 1.3480x over previous
//
#include <hip/hip_runtime.h>

#define NN 100000
#define EE 1600000
#define NBUCK ((NN + 255) >> 8)        // 391
#define CHUNK 8192
#define NPBLK ((EE + CHUNK - 1) / CHUNK) // 196

typedef __attribute__((ext_vector_type(8))) short short8_t;
typedef __attribute__((ext_vector_type(4))) float f32x4;

static __device__ inline unsigned short f2bf(float f) {
    unsigned int u = __float_as_uint(f);
    u += 0x7FFFu + ((u >> 16) & 1u);
    return (unsigned short)(u >> 16);
}
static __device__ inline float bf2f(unsigned short h) {
    return __uint_as_float(((unsigned int)h) << 16);
}

// ================= CSR build: contention-free radix partition =================
__global__ __launch_bounds__(256) void part_count(const int* __restrict__ ei,
                                                  int* __restrict__ cnt) {
    __shared__ int h[NBUCK];
    for (int i = threadIdx.x; i < NBUCK; i += 256) h[i] = 0;
    __syncthreads();
    int e0 = blockIdx.x * CHUNK;
    int e1 = e0 + CHUNK; if (e1 > EE) e1 = EE;
    for (int e = e0 + threadIdx.x; e < e1; e += 256)
        atomicAdd(&h[ei[EE + e] >> 8], 1);
    __syncthreads();
    for (int i = threadIdx.x; i < NBUCK; i += 256)
        cnt[blockIdx.x * NBUCK + i] = h[i];
}

__global__ void part_scan(const int* __restrict__ cnt, int* __restrict__ base,
                          int* __restrict__ bbase) {
    __shared__ int tot[512];
    int b = threadIdx.x;
    int t = 0;
    if (b < NBUCK)
        for (int k = 0; k < NPBLK; ++k) t += cnt[k * NBUCK + b];
    tot[b] = t;
    __syncthreads();
    for (int off = 1; off < 512; off <<= 1) {
        int u = (b >= off) ? tot[b - off] : 0;
        __syncthreads();
        tot[b] += u;
        __syncthreads();
    }
    int excl = tot[b] - t;
    if (b < NBUCK) {
        bbase[b] = excl;
        int run = excl;
        for (int k = 0; k < NPBLK; ++k) {
            base[k * NBUCK + b] = run;
            run += cnt[k * NBUCK + b];
        }
    }
    if (b == 0) bbase[NBUCK] = EE;
}

__global__ __launch_bounds__(256) void part_scatter(const int* __restrict__ ei,
                                                    const int* __restrict__ base,
                                                    unsigned int* __restrict__ bbuf) {
    __shared__ int lcur[NBUCK];
    for (int i = threadIdx.x; i < NBUCK; i += 256)
        lcur[i] = base[blockIdx.x * NBUCK + i];
    __syncthreads();
    int e0 = blockIdx.x * CHUNK;
    int e1 = e0 + CHUNK; if (e1 > EE) e1 = EE;
    for (int e = e0 + threadIdx.x; e < e1; e += 256) {
        int s = ei[e], d = ei[EE + e];
        int pos = atomicAdd(&lcur[d >> 8], 1);
        bbuf[pos] = (unsigned int)s | ((unsigned int)(d & 255) << 24);
    }
}

__global__ __launch_bounds__(256) void csr_build(const unsigned int* __restrict__ bbuf,
                                                 const int* __restrict__ bbase,
                                                 int* __restrict__ row_ptr,
                                                 int* __restrict__ col) {
    __shared__ int hist[256];
    __shared__ int sc[256];
    __shared__ int lcur[256];
    int b = blockIdx.x;
    int t = threadIdx.x;
    int n0 = b << 8;
    int nCnt = NN - n0; if (nCnt > 256) nCnt = 256;
    int es = bbase[b], ee2 = bbase[b + 1];
    hist[t] = 0;
    __syncthreads();
    for (int i = es + t; i < ee2; i += 256)
        atomicAdd(&hist[bbuf[i] >> 24], 1);
    __syncthreads();
    int v = hist[t];
    sc[t] = v;
    __syncthreads();
    for (int off = 1; off < 256; off <<= 1) {
        int u = (t >= off) ? sc[t - off] : 0;
        __syncthreads();
        sc[t] += u;
        __syncthreads();
    }
    int excl = sc[t] - v;
    if (t < nCnt) row_ptr[n0 + t] = es + excl;
    if (b == 0 && t == 0) row_ptr[NN] = EE;
    lcur[t] = excl;
    __syncthreads();
    for (int i = es + t; i < ee2; i += 256) {
        unsigned int pk = bbuf[i];
        int lpos = atomicAdd(&lcur[pk >> 24], 1);
        col[es + lpos] = (int)(pk & 0x00FFFFFFu);
    }
}

// ================= weight prep =================
// W[K (rows via ldw)][cols] f32 -> BT planes [128][stride] bf16 hi/lo at column-offset koff
__global__ void bsplit_kernel(const float* __restrict__ W, int ldw, int K, int N,
                              unsigned short* __restrict__ BThi,
                              unsigned short* __restrict__ BTlo,
                              int stride, int koff, int KPseg) {
    int k = blockIdx.x * 256 + threadIdx.x;
    int col = blockIdx.y;
    if (k >= KPseg) return;
    float v = (k < K && col < N) ? W[(size_t)k * ldw + col] : 0.f;
    unsigned short hi = f2bf(v);
    unsigned short lo = f2bf(v - bf2f(hi));
    BThi[(size_t)col * stride + koff + k] = hi;
    BTlo[(size_t)col * stride + koff + k] = lo;
}

// cvec[j] = sum_k b_feat[k] * W0[(40+k)*128 + j]
__global__ void cvec_kernel(const float* __restrict__ b_feat,
                            const float* __restrict__ W0, float* __restrict__ cvec) {
    int j = threadIdx.x;
    float s = 0.f;
    for (int k = 0; k < 128; ++k) s += b_feat[k] * W0[(40 + k) * 128 + j];
    cvec[j] = s;
}

// ================= split-bf16 MFMA GEMM (dual-A concat along K) ===================
// C[M,128] = [A1 | A2] @ B, B pre-split bf16 planes [128][bstride].
#define AHI 0
#define ALO 2048
#define BHI 4096
#define BLO 8192
template <int OUTBF16>
__global__ __launch_bounds__(256) void mfma_gemm_kernel(
    const float* __restrict__ A1, int lda1, int K1, int KP1,
    const float* __restrict__ A2, int lda2, int K2,
    int M,
    const unsigned short* __restrict__ BThi, const unsigned short* __restrict__ BTlo,
    int bstride, int KPtot,
    void* __restrict__ Cout, int ldc, int Nact, const float* __restrict__ bias)
{
    __shared__ __align__(16) unsigned short lds[12288];
    const int t = threadIdx.x;
    const int w = t >> 6, lane = t & 63;
    const int row0 = blockIdx.x * 64;
    const int rbase = (w & 1) * 32;
    const int cbase = (w >> 1) * 64;

    f32x4 acc[2][4];
#pragma unroll
    for (int i = 0; i < 2; ++i)
#pragma unroll
        for (int j = 0; j < 4; ++j) acc[i][j] = (f32x4){0.f, 0.f, 0.f, 0.f};

    const int arow = t >> 2;
    const int aslot = t & 3;
    const bool rowok = (row0 + arow) < M;
    const float* Arow1 = A1 + (size_t)(row0 + arow) * lda1;
    const float* Arow2 = A2 ? A2 + (size_t)(row0 + arow) * lda2 : nullptr;
    const int aoff = arow * 32 + (((aslot ^ ((arow >> 1) & 3))) << 3);

    for (int k0 = 0; k0 < KPtot; k0 += 32) {
        {
            const float* Asrc;
            int gk, Klim;
            if (k0 < KP1) { Asrc = Arow1; gk = k0 + aslot * 8; Klim = K1; }
            else          { Asrc = Arow2; gk = k0 - KP1 + aslot * 8; Klim = K2; }
            float a[8];
            if (rowok && gk + 8 <= Klim) {
                float4 v0 = *(const float4*)(Asrc + gk);
                float4 v1 = *(const float4*)(Asrc + gk + 4);
                a[0] = v0.x; a[1] = v0.y; a[2] = v0.z; a[3] = v0.w;
                a[4] = v1.x; a[5] = v1.y; a[6] = v1.z; a[7] = v1.w;
            } else {
#pragma unroll
                for (int j = 0; j < 8; ++j) a[j] = 0.f;
            }
            short8_t vh, vl;
#pragma unroll
            for (int j = 0; j < 8; ++j) {
                unsigned short hi = f2bf(a[j]);
                vh[j] = (short)hi;
                vl[j] = (short)f2bf(a[j] - bf2f(hi));
            }
            *(short8_t*)&lds[AHI + aoff] = vh;
            *(short8_t*)&lds[ALO + aoff] = vl;
        }
#pragma unroll
        for (int i = 0; i < 2; ++i) {
            int idx = t + i * 256;
            int col = idx >> 2, slot = idx & 3;
            int bo = col * 32 + ((slot ^ ((col >> 1) & 3)) << 3);
            size_t gbo = (size_t)col * bstride + k0 + slot * 8;
            *(short8_t*)&lds[BHI + bo] = *(const short8_t*)&BThi[gbo];
            *(short8_t*)&lds[BLO + bo] = *(const short8_t*)&BTlo[gbo];
        }
        __syncthreads();
        short8_t Ah[2], Al[2], Bh[4], Bl[4];
        const int fslot = lane >> 4;
#pragma unroll
        for (int rt = 0; rt < 2; ++rt) {
            int r = rbase + rt * 16 + (lane & 15);
            int off = r * 32 + ((fslot ^ ((r >> 1) & 3)) << 3);
            Ah[rt] = *(const short8_t*)&lds[AHI + off];
            Al[rt] = *(const short8_t*)&lds[ALO + off];
        }
#pragma unroll
        for (int ct = 0; ct < 4; ++ct) {
            int c = cbase + ct * 16 + (lane & 15);
            int off = c * 32 + ((fslot ^ ((c >> 1) & 3)) << 3);
            Bh[ct] = *(const short8_t*)&lds[BHI + off];
            Bl[ct] = *(const short8_t*)&lds[BLO + off];
        }
#pragma unroll
        for (int rt = 0; rt < 2; ++rt)
#pragma unroll
            for (int ct = 0; ct < 4; ++ct) {
                acc[rt][ct] = __builtin_amdgcn_mfma_f32_16x16x32_bf16(Ah[rt], Bh[ct], acc[rt][ct], 0, 0, 0);
                acc[rt][ct] = __builtin_amdgcn_mfma_f32_16x16x32_bf16(Ah[rt], Bl[ct], acc[rt][ct], 0, 0, 0);
                acc[rt][ct] = __builtin_amdgcn_mfma_f32_16x16x32_bf16(Al[rt], Bh[ct], acc[rt][ct], 0, 0, 0);
            }
        __syncthreads();
    }

#pragma unroll
    for (int rt = 0; rt < 2; ++rt) {
#pragma unroll
        for (int reg = 0; reg < 4; ++reg) {
            int r = row0 + rbase + rt * 16 + (lane >> 4) * 4 + reg;
            if (r >= M) continue;
#pragma unroll
            for (int ct = 0; ct < 4; ++ct) {
                int c = cbase + ct * 16 + (lane & 15);
                float v = acc[rt][ct][reg];
                if (bias) v += bias[c];
                if (OUTBF16) {
                    ((unsigned short*)Cout)[(size_t)r * 128 + c] = f2bf(v);
                } else {
                    if (c < Nact)
                        ((float*)Cout)[(size_t)r * ldc + c] = v;
                }
            }
        }
    }
}

// ================= attention coefficients from bf16 h =================
__global__ void attn_coef_bf16(const unsigned short* __restrict__ hb,
                               const float* __restrict__ att_src,
                               const float* __restrict__ att_dst,
                               float* __restrict__ a_src, float* __restrict__ a_dst) {
    int n = (blockIdx.x * 256 + threadIdx.x) >> 6;
    if (n >= NN) return;
    int lane = threadIdx.x & 63;
    unsigned int hv = ((const unsigned int*)hb)[n * 64 + lane];
    float hx = __uint_as_float(hv << 16);
    float hy = __uint_as_float(hv & 0xFFFF0000u);
    int c0 = lane * 2;
    float vs = hx * att_src[c0] + hy * att_src[c0 + 1];
    float vd = hx * att_dst[c0] + hy * att_dst[c0 + 1];
#pragma unroll
    for (int off = 1; off <= 16; off <<= 1) {
        vs += __shfl_xor(vs, off);
        vd += __shfl_xor(vd, off);
    }
    if ((lane & 31) == 0) {
        int head = lane >> 5;
        a_src[n * 2 + head] = vs;
        a_dst[n * 2 + head] = vd;
    }
}

// ================= fused GAT aggregation (CSR gather, 4-deep pipelined) ============
template <int RELU>
__global__ void gat_agg_fused(const int* __restrict__ row_ptr, const int* __restrict__ col,
                              const float* __restrict__ a_src, const float* __restrict__ a_dst,
                              const unsigned short* __restrict__ hb,
                              const float* __restrict__ bias, float* __restrict__ out) {
    int wid = (blockIdx.x * 256 + threadIdx.x) >> 6;
    if (wid >= NN) return;
    int lane = threadIdx.x & 63;
    int head = lane >> 5;
    const unsigned int* h2 = (const unsigned int*)hb;

    float2 ad = ((const float2*)a_dst)[wid];
    float2 asf = ((const float2*)a_src)[wid];
    float e0 = (head ? asf.y : asf.x) + (head ? ad.y : ad.x);
    e0 = e0 > 0.f ? e0 : 0.2f * e0;
    float w = __expf(e0);
    unsigned int hv = h2[wid * 64 + lane];
    float accx = w * __uint_as_float(hv << 16);
    float accy = w * __uint_as_float(hv & 0xFFFF0000u);
    float den = w;

    int rs = row_ptr[wid], re = row_ptr[wid + 1];
    for (int base = rs; base < re; base += 64) {
        int cnt = re - base;
        if (cnt > 64) cnt = 64;
        int sL = 0;
        float w0 = 0.f, w1 = 0.f;
        if (lane < cnt) {
            sL = col[base + lane];
            float2 as = ((const float2*)a_src)[sL];
            float t0 = as.x + ad.x;
            float t1 = as.y + ad.y;
            t0 = t0 > 0.f ? t0 : 0.2f * t0;
            t1 = t1 > 0.f ? t1 : 0.2f * t1;
            w0 = __expf(t0);
            w1 = __expf(t1);
        }
        int i = 0;
        for (; i + 4 <= cnt; i += 4) {
            int s0 = __shfl(sL, i);
            int s1 = __shfl(sL, i + 1);
            int s2 = __shfl(sL, i + 2);
            int s3 = __shfl(sL, i + 3);
            unsigned int g0 = h2[s0 * 64 + lane];
            unsigned int g1 = h2[s1 * 64 + lane];
            unsigned int g2 = h2[s2 * 64 + lane];
            unsigned int g3 = h2[s3 * 64 + lane];
            float wa0 = __shfl(w0, i),     wb0 = __shfl(w1, i);
            float wa1 = __shfl(w0, i + 1), wb1 = __shfl(w1, i + 1);
            float wa2 = __shfl(w0, i + 2), wb2 = __shfl(w1, i + 2);
            float wa3 = __shfl(w0, i + 3), wb3 = __shfl(w1, i + 3);
            float ws0 = head ? wb0 : wa0;
            float ws1 = head ? wb1 : wa1;
            float ws2 = head ? wb2 : wa2;
            float ws3 = head ? wb3 : wa3;
            accx += ws0 * __uint_as_float(g0 << 16);
            accy += ws0 * __uint_as_float(g0 & 0xFFFF0000u);
            accx += ws1 * __uint_as_float(g1 << 16);
            accy += ws1 * __uint_as_float(g1 & 0xFFFF0000u);
            accx += ws2 * __uint_as_float(g2 << 16);
            accy += ws2 * __uint_as_float(g2 & 0xFFFF0000u);
            accx += ws3 * __uint_as_float(g3 << 16);
            accy += ws3 * __uint_as_float(g3 & 0xFFFF0000u);
            den += ws0 + ws1 + ws2 + ws3;
        }
        for (; i < cnt; ++i) {
            int s = __shfl(sL, i);
            float wa = __shfl(w0, i);
            float wb = __shfl(w1, i);
            float ws = head ? wb : wa;
            unsigned int hs = h2[s * 64 + lane];
            accx += ws * __uint_as_float(hs << 16);
            accy += ws * __uint_as_float(hs & 0xFFFF0000u);
            den += ws;
        }
    }
    float inv = 1.f / (den + 1e-16f);
    float2 b2 = ((const float2*)bias)[lane];
    float ox = accx * inv + b2.x;
    float oy = accy * inv + b2.y;
    if (RELU) { ox = fmaxf(ox, 0.f); oy = fmaxf(oy, 0.f); }
    ((float2*)out)[wid * 64 + lane] = make_float2(ox, oy);
}

extern "C" void kernel_launch(void* const* d_in, const int* in_sizes, int n_in,
                              void* d_out, int out_size, void* d_ws, size_t ws_size,
                              hipStream_t stream) {
    const float* logits   = (const float*)d_in[0];
    const float* features = (const float*)d_in[1];
    const int*   ei       = (const int*)d_in[2];
    const float* W_feat   = (const float*)d_in[3];
    const float* b_feat   = (const float*)d_in[4];
    const float* W0       = (const float*)d_in[5];
    const float* att_src0 = (const float*)d_in[6];
    const float* att_dst0 = (const float*)d_in[7];
    const float* bias0    = (const float*)d_in[8];
    const float* W1       = (const float*)d_in[9];
    const float* att_src1 = (const float*)d_in[10];
    const float* att_dst1 = (const float*)d_in[11];
    const float* bias1    = (const float*)d_in[12];
    const float* W_out    = (const float*)d_in[13];
    const float* b_out    = (const float*)d_in[14];
    float* out = (float*)d_out;

    float* agg    = (float*)d_ws;                       // NN*128
    float* a_srcb = agg + (size_t)NN * 128;             // NN*2
    float* a_dstb = a_srcb + (size_t)NN * 2;            // NN*2
    float* Wc     = a_dstb + (size_t)NN * 2;            // 256*128
    float* cvec   = Wc + 256 * 128;                     // 128
    unsigned short* hbuf = (unsigned short*)(cvec + 128);      // NN*128 bf16
    unsigned short* BT0hi = hbuf + (size_t)NN * 128;    // 128*320
    unsigned short* BT0lo = BT0hi + 128 * 320;
    unsigned short* BTbhi = BT0lo + 128 * 320;          // 128*128 (W0b planes)
    unsigned short* BTblo = BTbhi + 128 * 128;
    unsigned short* BT1hi = BTblo + 128 * 128;          // 128*128
    unsigned short* BT1lo = BT1hi + 128 * 128;
    unsigned short* BTohi = BT1lo + 128 * 128;          // 128*128
    unsigned short* BTolo = BTohi + 128 * 128;
    int* row_ptr = (int*)(BTolo + 128 * 128);           // NN+1
    int* colbuf  = row_ptr + NN + 1;                    // EE
    int* cnt     = colbuf + EE;                         // NPBLK*NBUCK
    int* pbase   = cnt + NPBLK * NBUCK;                 // NPBLK*NBUCK
    int* bbase   = pbase + NPBLK * NBUCK;               // NBUCK+1
    unsigned int* bbuf = (unsigned int*)agg;            // EE u32, aliases agg (dead until L0 agg)

    dim3 blk(256);
    const int gemmGrid = (NN + 63) / 64;
    const int nodeWaveGrid = (NN + 3) / 4;

    // ---- CSR build (contention-free radix partition) ----
    part_count<<<dim3(NPBLK), blk, 0, stream>>>(ei, cnt);
    part_scan<<<dim3(1), dim3(512), 0, stream>>>(cnt, pbase, bbase);
    part_scatter<<<dim3(NPBLK), blk, 0, stream>>>(ei, pbase, bbuf);
    csr_build<<<dim3(NBUCK), blk, 0, stream>>>(bbuf, bbase, row_ptr, colbuf);

    // ---- weight prep ----
    // W0a (rows 0..40 of W0) -> BT0 segment [0,64)
    bsplit_kernel<<<dim3(1, 128), blk, 0, stream>>>(W0, 128, 40, 128, BT0hi, BT0lo, 320, 0, 64);
    // W0b (rows 40..168 of W0) -> BTb planes
    bsplit_kernel<<<dim3(1, 128), blk, 0, stream>>>(W0 + 40 * 128, 128, 128, 128, BTbhi, BTblo, 128, 0, 128);
    // Wc = W_feat @ W0b  (256x128, f32 out)
    mfma_gemm_kernel<0><<<dim3(4), blk, 0, stream>>>(
        W_feat, 128, 128, 128, nullptr, 0, 0, 256,
        BTbhi, BTblo, 128, 128, Wc, 128, 128, nullptr);
    cvec_kernel<<<dim3(1), dim3(128), 0, stream>>>(b_feat, W0, cvec);
    // Wc -> BT0 segment [64,320)
    bsplit_kernel<<<dim3(1, 128), blk, 0, stream>>>(Wc, 128, 256, 128, BT0hi, BT0lo, 320, 64, 256);
    // W1, W_out
    bsplit_kernel<<<dim3(1, 128), blk, 0, stream>>>(W1, 128, 128, 128, BT1hi, BT1lo, 128, 0, 128);
    bsplit_kernel<<<dim3(1, 128), blk, 0, stream>>>(W_out, 40, 128, 40, BTohi, BTolo, 128, 0, 128);

    // ---- GAT layer 0 (fused input assembly): h0 = logits@W0a + features@Wc + cvec ----
    mfma_gemm_kernel<1><<<dim3(gemmGrid), blk, 0, stream>>>(
        logits, 40, 40, 64, features, 256, 256, NN,
        BT0hi, BT0lo, 320, 320, hbuf, 128, 128, cvec);
    attn_coef_bf16<<<dim3(nodeWaveGrid), blk, 0, stream>>>(hbuf, att_src0, att_dst0, a_srcb, a_dstb);
    // bbuf (aliasing agg) dead from here; agg becomes live
    gat_agg_fused<1><<<dim3(nodeWaveGrid), blk, 0, stream>>>(
        row_ptr, colbuf, a_srcb, a_dstb, hbuf, bias0, agg);

    // ---- GAT layer 1 ----
    mfma_gemm_kernel<1><<<dim3(gemmGrid), blk, 0, stream>>>(
        agg, 128, 128, 128, nullptr, 0, 0, NN,
        BT1hi, BT1lo, 128, 128, hbuf, 128, 128, nullptr);
    attn_coef_bf16<<<dim3(nodeWaveGrid), blk, 0, stream>>>(hbuf, att_src1, att_dst1, a_srcb, a_dstb);
    gat_agg_fused<0><<<dim3(nodeWaveGrid), blk, 0, stream>>>(
        row_ptr, colbuf, a_srcb, a_dstb, hbuf, bias1, agg);

    // ---- output projection ----
    mfma_gemm_kernel<0><<<dim3(gemmGrid), blk, 0, stream>>>(
        agg, 128, 128, 128, nullptr, 0, 0, NN,
        BTohi, BTolo, 128, 128, out, 40, 40, b_out);
}

// Round 9
// 332.456 us; speedup vs baseline: 3.0014x; 1.0464x over previous
//
#include <hip/hip_runtime.h>

#define NN 100000
#define EE 1600000
#define NBUCK ((NN + 255) >> 8)        // 391
#define CHUNK 8192
#define NPBLK ((EE + CHUNK - 1) / CHUNK) // 196

typedef __attribute__((ext_vector_type(8))) short short8_t;
typedef __attribute__((ext_vector_type(4))) float f32x4;

static __device__ inline unsigned short f2bf(float f) {
    unsigned int u = __float_as_uint(f);
    u += 0x7FFFu + ((u >> 16) & 1u);
    return (unsigned short)(u >> 16);
}
static __device__ inline float bf2f(unsigned short h) {
    return __uint_as_float(((unsigned int)h) << 16);
}

// ================= CSR build: contention-free radix partition =================
__global__ __launch_bounds__(256) void part_count(const int* __restrict__ ei,
                                                  int* __restrict__ cnt) {
    __shared__ int h[NBUCK];
    for (int i = threadIdx.x; i < NBUCK; i += 256) h[i] = 0;
    __syncthreads();
    int e0 = blockIdx.x * CHUNK;
    int e1 = e0 + CHUNK; if (e1 > EE) e1 = EE;
    for (int e = e0 + threadIdx.x; e < e1; e += 256)
        atomicAdd(&h[ei[EE + e] >> 8], 1);
    __syncthreads();
    for (int i = threadIdx.x; i < NBUCK; i += 256)
        cnt[blockIdx.x * NBUCK + i] = h[i];
}

__global__ void part_scan(const int* __restrict__ cnt, int* __restrict__ base,
                          int* __restrict__ bbase) {
    __shared__ int tot[512];
    int b = threadIdx.x;
    int t = 0;
    if (b < NBUCK)
        for (int k = 0; k < NPBLK; ++k) t += cnt[k * NBUCK + b];
    tot[b] = t;
    __syncthreads();
    for (int off = 1; off < 512; off <<= 1) {
        int u = (b >= off) ? tot[b - off] : 0;
        __syncthreads();
        tot[b] += u;
        __syncthreads();
    }
    int excl = tot[b] - t;
    if (b < NBUCK) {
        bbase[b] = excl;
        int run = excl;
        for (int k = 0; k < NPBLK; ++k) {
            base[k * NBUCK + b] = run;
            run += cnt[k * NBUCK + b];
        }
    }
    if (b == 0) bbase[NBUCK] = EE;
}

__global__ __launch_bounds__(256) void part_scatter(const int* __restrict__ ei,
                                                    const int* __restrict__ base,
                                                    unsigned int* __restrict__ bbuf) {
    __shared__ int lcur[NBUCK];
    for (int i = threadIdx.x; i < NBUCK; i += 256)
        lcur[i] = base[blockIdx.x * NBUCK + i];
    __syncthreads();
    int e0 = blockIdx.x * CHUNK;
    int e1 = e0 + CHUNK; if (e1 > EE) e1 = EE;
    for (int e = e0 + threadIdx.x; e < e1; e += 256) {
        int s = ei[e], d = ei[EE + e];
        int pos = atomicAdd(&lcur[d >> 8], 1);
        bbuf[pos] = (unsigned int)s | ((unsigned int)(d & 255) << 24);
    }
}

__global__ __launch_bounds__(256) void csr_build(const unsigned int* __restrict__ bbuf,
                                                 const int* __restrict__ bbase,
                                                 int* __restrict__ row_ptr,
                                                 int* __restrict__ col) {
    __shared__ int hist[256];
    __shared__ int sc[256];
    __shared__ int lcur[256];
    int b = blockIdx.x;
    int t = threadIdx.x;
    int n0 = b << 8;
    int nCnt = NN - n0; if (nCnt > 256) nCnt = 256;
    int es = bbase[b], ee2 = bbase[b + 1];
    hist[t] = 0;
    __syncthreads();
    for (int i = es + t; i < ee2; i += 256)
        atomicAdd(&hist[bbuf[i] >> 24], 1);
    __syncthreads();
    int v = hist[t];
    sc[t] = v;
    __syncthreads();
    for (int off = 1; off < 256; off <<= 1) {
        int u = (t >= off) ? sc[t - off] : 0;
        __syncthreads();
        sc[t] += u;
        __syncthreads();
    }
    int excl = sc[t] - v;
    if (t < nCnt) row_ptr[n0 + t] = es + excl;
    if (b == 0 && t == 0) row_ptr[NN] = EE;
    lcur[t] = excl;
    __syncthreads();
    for (int i = es + t; i < ee2; i += 256) {
        unsigned int pk = bbuf[i];
        int lpos = atomicAdd(&lcur[pk >> 24], 1);
        col[es + lpos] = (int)(pk & 0x00FFFFFFu);
    }
}

// ================= weight prep =================
__global__ void bsplit_kernel(const float* __restrict__ W, int ldw, int K, int N,
                              unsigned short* __restrict__ BThi,
                              unsigned short* __restrict__ BTlo,
                              int stride, int koff, int KPseg) {
    int k = blockIdx.x * 256 + threadIdx.x;
    int col = blockIdx.y;
    if (k >= KPseg) return;
    float v = (k < K && col < N) ? W[(size_t)k * ldw + col] : 0.f;
    unsigned short hi = f2bf(v);
    unsigned short lo = f2bf(v - bf2f(hi));
    BThi[(size_t)col * stride + koff + k] = hi;
    BTlo[(size_t)col * stride + koff + k] = lo;
}

__global__ void cvec_kernel(const float* __restrict__ b_feat,
                            const float* __restrict__ W0, float* __restrict__ cvec) {
    int j = threadIdx.x;
    float s = 0.f;
    for (int k = 0; k < 128; ++k) s += b_feat[k] * W0[(40 + k) * 128 + j];
    cvec[j] = s;
}

// ================= split-bf16 MFMA GEMM, register-prefetch pipelined ==============
// ABF16=0: A f32 (dual-A concat along K), split on the fly (3 MFMA products).
// ABF16=1: A1 is bf16 [M][lda1], no split (2 MFMA products).
#define AHI 0
#define ALO 2048
#define BHI 4096
#define BLO 8192
template <int OUTBF16, int ABF16>
__global__ __launch_bounds__(256) void mfma_gemm_kernel(
    const void* __restrict__ A1v, int lda1, int K1, int KP1,
    const float* __restrict__ A2, int lda2, int K2,
    int M,
    const unsigned short* __restrict__ BThi, const unsigned short* __restrict__ BTlo,
    int bstride, int KPtot,
    void* __restrict__ Cout, int ldc, int Nact, const float* __restrict__ bias)
{
    __shared__ __align__(16) unsigned short lds[12288];
    const int t = threadIdx.x;
    const int w = t >> 6, lane = t & 63;
    const int row0 = blockIdx.x * 64;
    const int rbase = (w & 1) * 32;
    const int cbase = (w >> 1) * 64;

    f32x4 acc[2][4];
#pragma unroll
    for (int i = 0; i < 2; ++i)
#pragma unroll
        for (int j = 0; j < 4; ++j) acc[i][j] = (f32x4){0.f, 0.f, 0.f, 0.f};

    const int arow = t >> 2;
    const int aslot = t & 3;
    const bool rowok = (row0 + arow) < M;
    const int aoff = arow * 32 + (((aslot ^ ((arow >> 1) & 3))) << 3);

    // B staging geometry (constant per thread)
    const int bc0 = t >> 2,        bs0 = t & 3;
    const int bc1 = (t + 256) >> 2, bs1 = (t + 256) & 3;
    const int bo0 = bc0 * 32 + ((bs0 ^ ((bc0 >> 1) & 3)) << 3);
    const int bo1 = bc1 * 32 + ((bs1 ^ ((bc1 >> 1) & 3)) << 3);

    // prefetch registers
    float ra[8];
    short8_t rab;
    short8_t rbh0, rbl0, rbh1, rbl1;
    const short8_t zz = {0, 0, 0, 0, 0, 0, 0, 0};

#define LOADB(k0_) {                                                      \
        size_t g0_ = (size_t)bc0 * bstride + (k0_) + bs0 * 8;             \
        rbh0 = *(const short8_t*)&BThi[g0_];                              \
        rbl0 = *(const short8_t*)&BTlo[g0_];                              \
        size_t g1_ = (size_t)bc1 * bstride + (k0_) + bs1 * 8;             \
        rbh1 = *(const short8_t*)&BThi[g1_];                              \
        rbl1 = *(const short8_t*)&BTlo[g1_];                              \
    }

#define LOADA(k0_) {                                                      \
        if (ABF16) {                                                      \
            int gk = (k0_) + aslot * 8;                                   \
            if (rowok && gk + 8 <= K1) {                                  \
                const unsigned short* Ab =                                \
                    (const unsigned short*)A1v + (size_t)(row0 + arow) * lda1; \
                rab = *(const short8_t*)&Ab[gk];                          \
            } else rab = zz;                                              \
        } else {                                                          \
            const float* Asrc; int gk, Klim;                              \
            if ((k0_) < KP1) {                                            \
                Asrc = (const float*)A1v + (size_t)(row0 + arow) * lda1;  \
                gk = (k0_) + aslot * 8; Klim = K1;                        \
            } else {                                                      \
                Asrc = A2 + (size_t)(row0 + arow) * lda2;                 \
                gk = (k0_) - KP1 + aslot * 8; Klim = K2;                  \
            }                                                             \
            if (rowok && gk + 8 <= Klim) {                                \
                float4 v0 = *(const float4*)(Asrc + gk);                  \
                float4 v1 = *(const float4*)(Asrc + gk + 4);              \
                ra[0] = v0.x; ra[1] = v0.y; ra[2] = v0.z; ra[3] = v0.w;   \
                ra[4] = v1.x; ra[5] = v1.y; ra[6] = v1.z; ra[7] = v1.w;   \
            } else {                                                      \
                for (int j_ = 0; j_ < 8; ++j_) ra[j_] = 0.f;              \
            }                                                             \
        }                                                                 \
    }

    LOADA(0);
    LOADB(0);

    for (int k0 = 0; k0 < KPtot; k0 += 32) {
        // ---- write prefetched regs to LDS ----
        if (ABF16) {
            *(short8_t*)&lds[AHI + aoff] = rab;
        } else {
            short8_t vh, vl;
#pragma unroll
            for (int j = 0; j < 8; ++j) {
                unsigned short hi = f2bf(ra[j]);
                vh[j] = (short)hi;
                vl[j] = (short)f2bf(ra[j] - bf2f(hi));
            }
            *(short8_t*)&lds[AHI + aoff] = vh;
            *(short8_t*)&lds[ALO + aoff] = vl;
        }
        *(short8_t*)&lds[BHI + bo0] = rbh0;
        *(short8_t*)&lds[BLO + bo0] = rbl0;
        *(short8_t*)&lds[BHI + bo1] = rbh1;
        *(short8_t*)&lds[BLO + bo1] = rbl1;
        __syncthreads();

        // ---- issue next tile's global loads (latency hidden under MFMA) ----
        if (k0 + 32 < KPtot) {
            LOADA(k0 + 32);
            LOADB(k0 + 32);
        }

        // ---- fragments + MFMA ----
        short8_t Ah[2], Al[2], Bh[4], Bl[4];
        const int fslot = lane >> 4;
#pragma unroll
        for (int rt = 0; rt < 2; ++rt) {
            int r = rbase + rt * 16 + (lane & 15);
            int off = r * 32 + ((fslot ^ ((r >> 1) & 3)) << 3);
            Ah[rt] = *(const short8_t*)&lds[AHI + off];
            if (!ABF16) Al[rt] = *(const short8_t*)&lds[ALO + off];
        }
#pragma unroll
        for (int ct = 0; ct < 4; ++ct) {
            int c = cbase + ct * 16 + (lane & 15);
            int off = c * 32 + ((fslot ^ ((c >> 1) & 3)) << 3);
            Bh[ct] = *(const short8_t*)&lds[BHI + off];
            Bl[ct] = *(const short8_t*)&lds[BLO + off];
        }
#pragma unroll
        for (int rt = 0; rt < 2; ++rt)
#pragma unroll
            for (int ct = 0; ct < 4; ++ct) {
                acc[rt][ct] = __builtin_amdgcn_mfma_f32_16x16x32_bf16(Ah[rt], Bh[ct], acc[rt][ct], 0, 0, 0);
                acc[rt][ct] = __builtin_amdgcn_mfma_f32_16x16x32_bf16(Ah[rt], Bl[ct], acc[rt][ct], 0, 0, 0);
                if (!ABF16)
                    acc[rt][ct] = __builtin_amdgcn_mfma_f32_16x16x32_bf16(Al[rt], Bh[ct], acc[rt][ct], 0, 0, 0);
            }
        __syncthreads();
    }

#pragma unroll
    for (int rt = 0; rt < 2; ++rt) {
#pragma unroll
        for (int reg = 0; reg < 4; ++reg) {
            int r = row0 + rbase + rt * 16 + (lane >> 4) * 4 + reg;
            if (r >= M) continue;
#pragma unroll
            for (int ct = 0; ct < 4; ++ct) {
                int c = cbase + ct * 16 + (lane & 15);
                float v = acc[rt][ct][reg];
                if (bias) v += bias[c];
                if (OUTBF16) {
                    ((unsigned short*)Cout)[(size_t)r * 128 + c] = f2bf(v);
                } else {
                    if (c < Nact)
                        ((float*)Cout)[(size_t)r * ldc + c] = v;
                }
            }
        }
    }
#undef LOADA
#undef LOADB
}

// ================= attention coefficients from bf16 h =================
__global__ void attn_coef_bf16(const unsigned short* __restrict__ hb,
                               const float* __restrict__ att_src,
                               const float* __restrict__ att_dst,
                               float* __restrict__ a_src, float* __restrict__ a_dst) {
    int n = (blockIdx.x * 256 + threadIdx.x) >> 6;
    if (n >= NN) return;
    int lane = threadIdx.x & 63;
    unsigned int hv = ((const unsigned int*)hb)[n * 64 + lane];
    float hx = __uint_as_float(hv << 16);
    float hy = __uint_as_float(hv & 0xFFFF0000u);
    int c0 = lane * 2;
    float vs = hx * att_src[c0] + hy * att_src[c0 + 1];
    float vd = hx * att_dst[c0] + hy * att_dst[c0 + 1];
#pragma unroll
    for (int off = 1; off <= 16; off <<= 1) {
        vs += __shfl_xor(vs, off);
        vd += __shfl_xor(vd, off);
    }
    if ((lane & 31) == 0) {
        int head = lane >> 5;
        a_src[n * 2 + head] = vs;
        a_dst[n * 2 + head] = vd;
    }
}

// ================= fused GAT aggregation (CSR gather, 8-deep pipelined) ============
template <int RELU, int OUTBF16>
__global__ void gat_agg_fused(const int* __restrict__ row_ptr, const int* __restrict__ col,
                              const float* __restrict__ a_src, const float* __restrict__ a_dst,
                              const unsigned short* __restrict__ hb,
                              const float* __restrict__ bias, void* __restrict__ out) {
    int wid = (blockIdx.x * 256 + threadIdx.x) >> 6;
    if (wid >= NN) return;
    int lane = threadIdx.x & 63;
    int head = lane >> 5;
    const unsigned int* h2 = (const unsigned int*)hb;

    float2 ad = ((const float2*)a_dst)[wid];
    float2 asf = ((const float2*)a_src)[wid];
    float e0 = (head ? asf.y : asf.x) + (head ? ad.y : ad.x);
    e0 = e0 > 0.f ? e0 : 0.2f * e0;
    float w = __expf(e0);
    unsigned int hv = h2[wid * 64 + lane];
    float accx = w * __uint_as_float(hv << 16);
    float accy = w * __uint_as_float(hv & 0xFFFF0000u);
    float den = w;

    int rs = row_ptr[wid], re = row_ptr[wid + 1];
    for (int base = rs; base < re; base += 64) {
        int cnt = re - base;
        if (cnt > 64) cnt = 64;
        int sL = 0;
        float w0 = 0.f, w1 = 0.f;
        if (lane < cnt) {
            sL = col[base + lane];
            float2 as = ((const float2*)a_src)[sL];
            float t0 = as.x + ad.x;
            float t1 = as.y + ad.y;
            t0 = t0 > 0.f ? t0 : 0.2f * t0;
            t1 = t1 > 0.f ? t1 : 0.2f * t1;
            w0 = __expf(t0);
            w1 = __expf(t1);
        }
        int i = 0;
        for (; i + 8 <= cnt; i += 8) {
            int s[8];
            unsigned int g[8];
            float wa[8], wb[8];
#pragma unroll
            for (int j = 0; j < 8; ++j) s[j] = __shfl(sL, i + j);
#pragma unroll
            for (int j = 0; j < 8; ++j) g[j] = h2[s[j] * 64 + lane];
#pragma unroll
            for (int j = 0; j < 8; ++j) { wa[j] = __shfl(w0, i + j); wb[j] = __shfl(w1, i + j); }
#pragma unroll
            for (int j = 0; j < 8; ++j) {
                float ws = head ? wb[j] : wa[j];
                accx += ws * __uint_as_float(g[j] << 16);
                accy += ws * __uint_as_float(g[j] & 0xFFFF0000u);
                den += ws;
            }
        }
        for (; i + 4 <= cnt; i += 4) {
            int s[4];
            unsigned int g[4];
            float wa[4], wb[4];
#pragma unroll
            for (int j = 0; j < 4; ++j) s[j] = __shfl(sL, i + j);
#pragma unroll
            for (int j = 0; j < 4; ++j) g[j] = h2[s[j] * 64 + lane];
#pragma unroll
            for (int j = 0; j < 4; ++j) { wa[j] = __shfl(w0, i + j); wb[j] = __shfl(w1, i + j); }
#pragma unroll
            for (int j = 0; j < 4; ++j) {
                float ws = head ? wb[j] : wa[j];
                accx += ws * __uint_as_float(g[j] << 16);
                accy += ws * __uint_as_float(g[j] & 0xFFFF0000u);
                den += ws;
            }
        }
        for (; i < cnt; ++i) {
            int s = __shfl(sL, i);
            float wa = __shfl(w0, i);
            float wb = __shfl(w1, i);
            float ws = head ? wb : wa;
            unsigned int hs = h2[s * 64 + lane];
            accx += ws * __uint_as_float(hs << 16);
            accy += ws * __uint_as_float(hs & 0xFFFF0000u);
            den += ws;
        }
    }
    float inv = 1.f / (den + 1e-16f);
    float2 b2 = ((const float2*)bias)[lane];
    float ox = accx * inv + b2.x;
    float oy = accy * inv + b2.y;
    if (RELU) { ox = fmaxf(ox, 0.f); oy = fmaxf(oy, 0.f); }
    if (OUTBF16) {
        unsigned int pk = (unsigned int)f2bf(ox) | ((unsigned int)f2bf(oy) << 16);
        ((unsigned int*)out)[wid * 64 + lane] = pk;
    } else {
        ((float2*)out)[wid * 64 + lane] = make_float2(ox, oy);
    }
}

extern "C" void kernel_launch(void* const* d_in, const int* in_sizes, int n_in,
                              void* d_out, int out_size, void* d_ws, size_t ws_size,
                              hipStream_t stream) {
    const float* logits   = (const float*)d_in[0];
    const float* features = (const float*)d_in[1];
    const int*   ei       = (const int*)d_in[2];
    const float* W_feat   = (const float*)d_in[3];
    const float* b_feat   = (const float*)d_in[4];
    const float* W0       = (const float*)d_in[5];
    const float* att_src0 = (const float*)d_in[6];
    const float* att_dst0 = (const float*)d_in[7];
    const float* bias0    = (const float*)d_in[8];
    const float* W1       = (const float*)d_in[9];
    const float* att_src1 = (const float*)d_in[10];
    const float* att_dst1 = (const float*)d_in[11];
    const float* bias1    = (const float*)d_in[12];
    const float* W_out    = (const float*)d_in[13];
    const float* b_out    = (const float*)d_in[14];
    float* out = (float*)d_out;

    float* agg    = (float*)d_ws;                       // NN*128 f32 (also holds bf16 agg)
    float* a_srcb = agg + (size_t)NN * 128;             // NN*2
    float* a_dstb = a_srcb + (size_t)NN * 2;            // NN*2
    float* Wc     = a_dstb + (size_t)NN * 2;            // 256*128
    float* cvec   = Wc + 256 * 128;                     // 128
    unsigned short* hbuf = (unsigned short*)(cvec + 128);      // NN*128 bf16
    unsigned short* BT0hi = hbuf + (size_t)NN * 128;    // 128*320
    unsigned short* BT0lo = BT0hi + 128 * 320;
    unsigned short* BTbhi = BT0lo + 128 * 320;          // 128*128 (W0b planes)
    unsigned short* BTblo = BTbhi + 128 * 128;
    unsigned short* BT1hi = BTblo + 128 * 128;          // 128*128
    unsigned short* BT1lo = BT1hi + 128 * 128;
    unsigned short* BTohi = BT1lo + 128 * 128;          // 128*128
    unsigned short* BTolo = BTohi + 128 * 128;
    int* row_ptr = (int*)(BTolo + 128 * 128);           // NN+1
    int* colbuf  = row_ptr + NN + 1;                    // EE
    int* cnt     = colbuf + EE;                         // NPBLK*NBUCK
    int* pbase   = cnt + NPBLK * NBUCK;                 // NPBLK*NBUCK
    int* bbase   = pbase + NPBLK * NBUCK;               // NBUCK+1
    unsigned int* bbuf = (unsigned int*)agg;            // EE u32, aliases agg (dead until L0 agg)
    unsigned short* aggb = (unsigned short*)agg;        // bf16 view of agg for layer0 output

    dim3 blk(256);
    const int gemmGrid = (NN + 63) / 64;
    const int nodeWaveGrid = (NN + 3) / 4;

    // ---- CSR build (contention-free radix partition) ----
    part_count<<<dim3(NPBLK), blk, 0, stream>>>(ei, cnt);
    part_scan<<<dim3(1), dim3(512), 0, stream>>>(cnt, pbase, bbase);
    part_scatter<<<dim3(NPBLK), blk, 0, stream>>>(ei, pbase, bbuf);
    csr_build<<<dim3(NBUCK), blk, 0, stream>>>(bbuf, bbase, row_ptr, colbuf);

    // ---- weight prep ----
    bsplit_kernel<<<dim3(1, 128), blk, 0, stream>>>(W0, 128, 40, 128, BT0hi, BT0lo, 320, 0, 64);
    bsplit_kernel<<<dim3(1, 128), blk, 0, stream>>>(W0 + 40 * 128, 128, 128, 128, BTbhi, BTblo, 128, 0, 128);
    mfma_gemm_kernel<0, 0><<<dim3(4), blk, 0, stream>>>(
        W_feat, 128, 128, 128, nullptr, 0, 0, 256,
        BTbhi, BTblo, 128, 128, Wc, 128, 128, nullptr);
    cvec_kernel<<<dim3(1), dim3(128), 0, stream>>>(b_feat, W0, cvec);
    bsplit_kernel<<<dim3(1, 128), blk, 0, stream>>>(Wc, 128, 256, 128, BT0hi, BT0lo, 320, 64, 256);
    bsplit_kernel<<<dim3(1, 128), blk, 0, stream>>>(W1, 128, 128, 128, BT1hi, BT1lo, 128, 0, 128);
    bsplit_kernel<<<dim3(1, 128), blk, 0, stream>>>(W_out, 40, 128, 40, BTohi, BTolo, 128, 0, 128);

    // ---- GAT layer 0 (fused input assembly): h0 = logits@W0a + features@Wc + cvec ----
    mfma_gemm_kernel<1, 0><<<dim3(gemmGrid), blk, 0, stream>>>(
        logits, 40, 40, 64, features, 256, 256, NN,
        BT0hi, BT0lo, 320, 320, hbuf, 128, 128, cvec);
    attn_coef_bf16<<<dim3(nodeWaveGrid), blk, 0, stream>>>(hbuf, att_src0, att_dst0, a_srcb, a_dstb);
    // bbuf (aliasing agg) dead from here; agg becomes live (bf16 layer0 output)
    gat_agg_fused<1, 1><<<dim3(nodeWaveGrid), blk, 0, stream>>>(
        row_ptr, colbuf, a_srcb, a_dstb, hbuf, bias0, aggb);

    // ---- GAT layer 1 (bf16 A: 2-product MFMA, half A traffic) ----
    mfma_gemm_kernel<1, 1><<<dim3(gemmGrid), blk, 0, stream>>>(
        aggb, 128, 128, 128, nullptr, 0, 0, NN,
        BT1hi, BT1lo, 128, 128, hbuf, 128, 128, nullptr);
    attn_coef_bf16<<<dim3(nodeWaveGrid), blk, 0, stream>>>(hbuf, att_src1, att_dst1, a_srcb, a_dstb);
    gat_agg_fused<0, 0><<<dim3(nodeWaveGrid), blk, 0, stream>>>(
        row_ptr, colbuf, a_srcb, a_dstb, hbuf, bias1, agg);

    // ---- output projection ----
    mfma_gemm_kernel<0, 0><<<dim3(gemmGrid), blk, 0, stream>>>(
        agg, 128, 128, 128, nullptr, 0, 0, NN,
        BTohi, BTolo, 128, 128, out, 40, 40, b_out);
}

// Round 10
// 316.239 us; speedup vs baseline: 3.1553x; 1.0513x over previous
//
#include <hip/hip_runtime.h>

#define NN 100000
#define EE 1600000
#define NBUCK ((NN + 255) >> 8)        // 391
#define CHUNK 8192
#define NPBLK ((EE + CHUNK - 1) / CHUNK) // 196

typedef __attribute__((ext_vector_type(8))) short short8_t;
typedef __attribute__((ext_vector_type(4))) float f32x4;

static __device__ inline unsigned short f2bf(float f) {
    unsigned int u = __float_as_uint(f);
    u += 0x7FFFu + ((u >> 16) & 1u);
    return (unsigned short)(u >> 16);
}
static __device__ inline float bf2f(unsigned short h) {
    return __uint_as_float(((unsigned int)h) << 16);
}

// ================= CSR build: contention-free radix partition =================
__global__ __launch_bounds__(256) void part_count(const int* __restrict__ ei,
                                                  int* __restrict__ cnt) {
    __shared__ int h[NBUCK];
    for (int i = threadIdx.x; i < NBUCK; i += 256) h[i] = 0;
    __syncthreads();
    int e0 = blockIdx.x * CHUNK;
    int e1 = e0 + CHUNK; if (e1 > EE) e1 = EE;
    for (int e = e0 + threadIdx.x; e < e1; e += 256)
        atomicAdd(&h[ei[EE + e] >> 8], 1);
    __syncthreads();
    for (int i = threadIdx.x; i < NBUCK; i += 256)
        cnt[blockIdx.x * NBUCK + i] = h[i];
}

__global__ void part_scan(const int* __restrict__ cnt, int* __restrict__ base,
                          int* __restrict__ bbase) {
    __shared__ int tot[512];
    int b = threadIdx.x;
    int t = 0;
    if (b < NBUCK)
        for (int k = 0; k < NPBLK; ++k) t += cnt[k * NBUCK + b];
    tot[b] = t;
    __syncthreads();
    for (int off = 1; off < 512; off <<= 1) {
        int u = (b >= off) ? tot[b - off] : 0;
        __syncthreads();
        tot[b] += u;
        __syncthreads();
    }
    int excl = tot[b] - t;
    if (b < NBUCK) {
        bbase[b] = excl;
        int run = excl;
        for (int k = 0; k < NPBLK; ++k) {
            base[k * NBUCK + b] = run;
            run += cnt[k * NBUCK + b];
        }
    }
    if (b == 0) bbase[NBUCK] = EE;
}

__global__ __launch_bounds__(256) void part_scatter(const int* __restrict__ ei,
                                                    const int* __restrict__ base,
                                                    unsigned int* __restrict__ bbuf) {
    __shared__ int lcur[NBUCK];
    for (int i = threadIdx.x; i < NBUCK; i += 256)
        lcur[i] = base[blockIdx.x * NBUCK + i];
    __syncthreads();
    int e0 = blockIdx.x * CHUNK;
    int e1 = e0 + CHUNK; if (e1 > EE) e1 = EE;
    for (int e = e0 + threadIdx.x; e < e1; e += 256) {
        int s = ei[e], d = ei[EE + e];
        int pos = atomicAdd(&lcur[d >> 8], 1);
        bbuf[pos] = (unsigned int)s | ((unsigned int)(d & 255) << 24);
    }
}

__global__ __launch_bounds__(256) void csr_build(const unsigned int* __restrict__ bbuf,
                                                 const int* __restrict__ bbase,
                                                 int* __restrict__ row_ptr,
                                                 int* __restrict__ col) {
    __shared__ int hist[256];
    __shared__ int sc[256];
    __shared__ int lcur[256];
    int b = blockIdx.x;
    int t = threadIdx.x;
    int n0 = b << 8;
    int nCnt = NN - n0; if (nCnt > 256) nCnt = 256;
    int es = bbase[b], ee2 = bbase[b + 1];
    hist[t] = 0;
    __syncthreads();
    for (int i = es + t; i < ee2; i += 256)
        atomicAdd(&hist[bbuf[i] >> 24], 1);
    __syncthreads();
    int v = hist[t];
    sc[t] = v;
    __syncthreads();
    for (int off = 1; off < 256; off <<= 1) {
        int u = (t >= off) ? sc[t - off] : 0;
        __syncthreads();
        sc[t] += u;
        __syncthreads();
    }
    int excl = sc[t] - v;
    if (t < nCnt) row_ptr[n0 + t] = es + excl;
    if (b == 0 && t == 0) row_ptr[NN] = EE;
    lcur[t] = excl;
    __syncthreads();
    for (int i = es + t; i < ee2; i += 256) {
        unsigned int pk = bbuf[i];
        int lpos = atomicAdd(&lcur[pk >> 24], 1);
        col[es + lpos] = (int)(pk & 0x00FFFFFFu);
    }
}

// ================= weight prep =================
__global__ void bsplit_kernel(const float* __restrict__ W, int ldw, int K, int N,
                              unsigned short* __restrict__ BThi,
                              unsigned short* __restrict__ BTlo,
                              int stride, int koff, int KPseg) {
    int k = blockIdx.x * 256 + threadIdx.x;
    int col = blockIdx.y;
    if (k >= KPseg) return;
    float v = (k < K && col < N) ? W[(size_t)k * ldw + col] : 0.f;
    unsigned short hi = f2bf(v);
    unsigned short lo = f2bf(v - bf2f(hi));
    BThi[(size_t)col * stride + koff + k] = hi;
    BTlo[(size_t)col * stride + koff + k] = lo;
}

__global__ void cvec_kernel(const float* __restrict__ b_feat,
                            const float* __restrict__ W0, float* __restrict__ cvec) {
    int j = threadIdx.x;
    float s = 0.f;
    for (int k = 0; k < 128; ++k) s += b_feat[k] * W0[(40 + k) * 128 + j];
    cvec[j] = s;
}

// ======== split-bf16 MFMA GEMM, depth-2 register prefetch, fused attn dots ========
// ABF16=0: A f32 (dual-A concat along K), split hi/lo (3 MFMA products).
// ABF16=1: A1 bf16 [M][lda1] (2 products).  NCT: col-tiles per wave (4 -> BN=128, 2 -> BN=64).
// ATTN: epilogue computes a_src/a_dst row dots (requires NCT=4).
// Requires KPtot % 64 == 0.
#define AHI 0
#define ALO 2048
#define BHI 4096
#define BLO 8192
template <int OUTBF16, int ABF16, int ATTN, int NCT>
__global__ __launch_bounds__(256) void mfma_gemm_kernel(
    const void* __restrict__ A1v, int lda1, int K1, int KP1,
    const float* __restrict__ A2, int lda2, int K2,
    int M,
    const unsigned short* __restrict__ BThi, const unsigned short* __restrict__ BTlo,
    int bstride, int KPtot,
    void* __restrict__ Cout, int ldc, int Nact, const float* __restrict__ bias,
    const float* __restrict__ att_src, const float* __restrict__ att_dst,
    float* __restrict__ a_srcO, float* __restrict__ a_dstO)
{
    __shared__ __align__(16) unsigned short lds[12288];
    const int t = threadIdx.x;
    const int w = t >> 6, lane = t & 63;
    const int row0 = blockIdx.x * 64;
    const int rbase = (w & 1) * 32;
    const int cbase = (NCT == 4) ? (w >> 1) * 64 : (w >> 1) * 32;

    f32x4 acc[2][NCT];
#pragma unroll
    for (int i = 0; i < 2; ++i)
#pragma unroll
        for (int j = 0; j < NCT; ++j) acc[i][j] = (f32x4){0.f, 0.f, 0.f, 0.f};

    const int arow = t >> 2;
    const int aslot = t & 3;
    const bool rowok = (row0 + arow) < M;
    const int aoff = arow * 32 + (((aslot ^ ((arow >> 1) & 3))) << 3);

    const int bc0 = t >> 2,         bs0 = t & 3;
    const int bc1 = (t + 256) >> 2, bs1 = (t + 256) & 3;
    const int bo0 = bc0 * 32 + ((bs0 ^ ((bc0 >> 1) & 3)) << 3);
    const int bo1 = bc1 * 32 + ((bs1 ^ ((bc1 >> 1) & 3)) << 3);

    // two prefetch register sets
    float ra0[8], ra1[8];
    short8_t rab0, rab1;
    short8_t bh0a, bl0a, bh1a, bl1a;   // set0
    short8_t bh0b, bl0b, bh1b, bl1b;   // set1
    const short8_t zz = {0, 0, 0, 0, 0, 0, 0, 0};

#define LOADB_(k0_, H0, L0, H1, L1) {                                     \
        size_t g0_ = (size_t)bc0 * bstride + (k0_) + bs0 * 8;             \
        H0 = *(const short8_t*)&BThi[g0_];                                \
        L0 = *(const short8_t*)&BTlo[g0_];                                \
        if (NCT == 4) {                                                   \
            size_t g1_ = (size_t)bc1 * bstride + (k0_) + bs1 * 8;         \
            H1 = *(const short8_t*)&BThi[g1_];                            \
            L1 = *(const short8_t*)&BTlo[g1_];                            \
        }                                                                 \
    }

#define LOADA_(k0_, RA, RAB) {                                            \
        if (ABF16) {                                                      \
            int gk = (k0_) + aslot * 8;                                   \
            if (rowok && gk + 8 <= K1) {                                  \
                const unsigned short* Ab =                                \
                    (const unsigned short*)A1v + (size_t)(row0 + arow) * lda1; \
                RAB = *(const short8_t*)&Ab[gk];                          \
            } else RAB = zz;                                              \
        } else {                                                          \
            const float* Asrc; int gk, Klim;                              \
            if ((k0_) < KP1) {                                            \
                Asrc = (const float*)A1v + (size_t)(row0 + arow) * lda1;  \
                gk = (k0_) + aslot * 8; Klim = K1;                        \
            } else {                                                      \
                Asrc = A2 + (size_t)(row0 + arow) * lda2;                 \
                gk = (k0_) - KP1 + aslot * 8; Klim = K2;                  \
            }                                                             \
            if (rowok && gk + 8 <= Klim) {                                \
                float4 v0 = *(const float4*)(Asrc + gk);                  \
                float4 v1 = *(const float4*)(Asrc + gk + 4);              \
                RA[0] = v0.x; RA[1] = v0.y; RA[2] = v0.z; RA[3] = v0.w;   \
                RA[4] = v1.x; RA[5] = v1.y; RA[6] = v1.z; RA[7] = v1.w;   \
            } else {                                                      \
                for (int j_ = 0; j_ < 8; ++j_) RA[j_] = 0.f;              \
            }                                                             \
        }                                                                 \
    }

#define STAGE_(RA, RAB, H0, L0, H1, L1) {                                 \
        if (ABF16) {                                                      \
            *(short8_t*)&lds[AHI + aoff] = RAB;                           \
        } else {                                                          \
            short8_t vh_, vl_;                                            \
            for (int j_ = 0; j_ < 8; ++j_) {                              \
                unsigned short hi_ = f2bf(RA[j_]);                        \
                vh_[j_] = (short)hi_;                                     \
                vl_[j_] = (short)f2bf(RA[j_] - bf2f(hi_));                \
            }                                                             \
            *(short8_t*)&lds[AHI + aoff] = vh_;                           \
            *(short8_t*)&lds[ALO + aoff] = vl_;                           \
        }                                                                 \
        *(short8_t*)&lds[BHI + bo0] = H0;                                 \
        *(short8_t*)&lds[BLO + bo0] = L0;                                 \
        if (NCT == 4) {                                                   \
            *(short8_t*)&lds[BHI + bo1] = H1;                             \
            *(short8_t*)&lds[BLO + bo1] = L1;                             \
        }                                                                 \
    }

#define COMPUTE_() {                                                      \
        short8_t Ah[2], Al[2], Bh[NCT], Bl[NCT];                          \
        const int fslot = lane >> 4;                                      \
        for (int rt = 0; rt < 2; ++rt) {                                  \
            int r = rbase + rt * 16 + (lane & 15);                        \
            int off = r * 32 + ((fslot ^ ((r >> 1) & 3)) << 3);           \
            Ah[rt] = *(const short8_t*)&lds[AHI + off];                   \
            if (!ABF16) Al[rt] = *(const short8_t*)&lds[ALO + off];       \
        }                                                                 \
        for (int ct = 0; ct < NCT; ++ct) {                                \
            int c = cbase + ct * 16 + (lane & 15);                        \
            int off = c * 32 + ((fslot ^ ((c >> 1) & 3)) << 3);           \
            Bh[ct] = *(const short8_t*)&lds[BHI + off];                   \
            Bl[ct] = *(const short8_t*)&lds[BLO + off];                   \
        }                                                                 \
        for (int rt = 0; rt < 2; ++rt)                                    \
            for (int ct = 0; ct < NCT; ++ct) {                            \
                acc[rt][ct] = __builtin_amdgcn_mfma_f32_16x16x32_bf16(Ah[rt], Bh[ct], acc[rt][ct], 0, 0, 0); \
                acc[rt][ct] = __builtin_amdgcn_mfma_f32_16x16x32_bf16(Ah[rt], Bl[ct], acc[rt][ct], 0, 0, 0); \
                if (!ABF16)                                               \
                    acc[rt][ct] = __builtin_amdgcn_mfma_f32_16x16x32_bf16(Al[rt], Bh[ct], acc[rt][ct], 0, 0, 0); \
            }                                                             \
    }

    LOADA_(0, ra0, rab0);
    LOADB_(0, bh0a, bl0a, bh1a, bl1a);
    LOADA_(32, ra1, rab1);
    LOADB_(32, bh0b, bl0b, bh1b, bl1b);

    for (int k0 = 0; k0 < KPtot; k0 += 64) {
        STAGE_(ra0, rab0, bh0a, bl0a, bh1a, bl1a);
        __syncthreads();
        if (k0 + 64 < KPtot) {
            LOADA_(k0 + 64, ra0, rab0);
            LOADB_(k0 + 64, bh0a, bl0a, bh1a, bl1a);
        }
        COMPUTE_();
        __syncthreads();

        STAGE_(ra1, rab1, bh0b, bl0b, bh1b, bl1b);
        __syncthreads();
        if (k0 + 96 < KPtot) {
            LOADA_(k0 + 96, ra1, rab1);
            LOADB_(k0 + 96, bh0b, bl0b, bh1b, bl1b);
        }
        COMPUTE_();
        __syncthreads();
    }

    // ---- epilogue ----
#pragma unroll
    for (int rt = 0; rt < 2; ++rt) {
#pragma unroll
        for (int reg = 0; reg < 4; ++reg) {
            int r = row0 + rbase + rt * 16 + (lane >> 4) * 4 + reg;
            if (ATTN) {
                float ps = 0.f, pd = 0.f;
#pragma unroll
                for (int ct = 0; ct < NCT; ++ct) {
                    int c = cbase + ct * 16 + (lane & 15);
                    ps += acc[rt][ct][reg] * att_src[c];
                    pd += acc[rt][ct][reg] * att_dst[c];
                }
#pragma unroll
                for (int off = 1; off < 16; off <<= 1) {
                    ps += __shfl_xor(ps, off);
                    pd += __shfl_xor(pd, off);
                }
                if (r < M && (lane & 15) == 0) {
                    int head = w >> 1;
                    a_srcO[r * 2 + head] = ps;
                    a_dstO[r * 2 + head] = pd;
                }
            }
            if (r >= M) continue;
#pragma unroll
            for (int ct = 0; ct < NCT; ++ct) {
                int c = cbase + ct * 16 + (lane & 15);
                float v = acc[rt][ct][reg];
                if (bias) v += bias[c];
                if (OUTBF16) {
                    ((unsigned short*)Cout)[(size_t)r * 128 + c] = f2bf(v);
                } else {
                    if (c < Nact)
                        ((float*)Cout)[(size_t)r * ldc + c] = v;
                }
            }
        }
    }
#undef LOADA_
#undef LOADB_
#undef STAGE_
#undef COMPUTE_
}

// ========== fused GAT aggregation (CSR gather, head-split weight batches) ==========
// one wave per node; lane owns channels {2*lane, 2*lane+1}; channel-head hc = lane>>5.
// weight batch of 32 edges: lanes 0-31 compute head-0 w, lanes 32-63 head-1 w.
template <int RELU, int OUTBF16>
__global__ void gat_agg_fused(const int* __restrict__ row_ptr, const int* __restrict__ col,
                              const float* __restrict__ a_src, const float* __restrict__ a_dst,
                              const unsigned short* __restrict__ hb,
                              const float* __restrict__ bias, void* __restrict__ out) {
    int wid = (blockIdx.x * 256 + threadIdx.x) >> 6;
    if (wid >= NN) return;
    int lane = threadIdx.x & 63;
    int hc = lane >> 5;
    const unsigned int* h2 = (const unsigned int*)hb;

    float2 ad = ((const float2*)a_dst)[wid];
    float2 asf = ((const float2*)a_src)[wid];
    float adh = hc ? ad.y : ad.x;                 // dst coef for this lane's half
    float e0 = (hc ? asf.y : asf.x) + adh;
    e0 = e0 > 0.f ? e0 : 0.2f * e0;
    float w = __expf(e0);
    unsigned int hv = h2[wid * 64 + lane];
    float accx = w * __uint_as_float(hv << 16);
    float accy = w * __uint_as_float(hv & 0xFFFF0000u);
    float den = w;
    const int shbase = hc << 5;

    int rs = row_ptr[wid], re = row_ptr[wid + 1];
    for (int base = rs; base < re; base += 32) {
        int cnt = re - base;
        if (cnt > 32) cnt = 32;
        int eidx = lane & 31;
        int sL = 0;
        float wL = 0.f;
        if (eidx < cnt) {
            sL = col[base + eidx];
            float2 as = ((const float2*)a_src)[sL];
            float tt = (hc ? as.y : as.x) + adh;  // weight head == lane half
            tt = tt > 0.f ? tt : 0.2f * tt;
            wL = __expf(tt);
        }
        int i = 0;
        for (; i + 8 <= cnt; i += 8) {
            int s[8];
            unsigned int g[8];
            float ws[8];
#pragma unroll
            for (int j = 0; j < 8; ++j) s[j] = __shfl(sL, shbase + i + j);
#pragma unroll
            for (int j = 0; j < 8; ++j) g[j] = h2[s[j] * 64 + lane];
#pragma unroll
            for (int j = 0; j < 8; ++j) ws[j] = __shfl(wL, shbase + i + j);
#pragma unroll
            for (int j = 0; j < 8; ++j) {
                accx += ws[j] * __uint_as_float(g[j] << 16);
                accy += ws[j] * __uint_as_float(g[j] & 0xFFFF0000u);
                den += ws[j];
            }
        }
        for (; i + 4 <= cnt; i += 4) {
            int s[4];
            unsigned int g[4];
            float ws[4];
#pragma unroll
            for (int j = 0; j < 4; ++j) s[j] = __shfl(sL, shbase + i + j);
#pragma unroll
            for (int j = 0; j < 4; ++j) g[j] = h2[s[j] * 64 + lane];
#pragma unroll
            for (int j = 0; j < 4; ++j) ws[j] = __shfl(wL, shbase + i + j);
#pragma unroll
            for (int j = 0; j < 4; ++j) {
                accx += ws[j] * __uint_as_float(g[j] << 16);
                accy += ws[j] * __uint_as_float(g[j] & 0xFFFF0000u);
                den += ws[j];
            }
        }
        for (; i < cnt; ++i) {
            int s = __shfl(sL, shbase + i);
            float ws = __shfl(wL, shbase + i);
            unsigned int hs = h2[s * 64 + lane];
            accx += ws * __uint_as_float(hs << 16);
            accy += ws * __uint_as_float(hs & 0xFFFF0000u);
            den += ws;
        }
    }
    float inv = 1.f / (den + 1e-16f);
    float2 b2 = ((const float2*)bias)[lane];
    float ox = accx * inv + b2.x;
    float oy = accy * inv + b2.y;
    if (RELU) { ox = fmaxf(ox, 0.f); oy = fmaxf(oy, 0.f); }
    if (OUTBF16) {
        unsigned int pk = (unsigned int)f2bf(ox) | ((unsigned int)f2bf(oy) << 16);
        ((unsigned int*)out)[wid * 64 + lane] = pk;
    } else {
        ((float2*)out)[wid * 64 + lane] = make_float2(ox, oy);
    }
}

extern "C" void kernel_launch(void* const* d_in, const int* in_sizes, int n_in,
                              void* d_out, int out_size, void* d_ws, size_t ws_size,
                              hipStream_t stream) {
    const float* logits   = (const float*)d_in[0];
    const float* features = (const float*)d_in[1];
    const int*   ei       = (const int*)d_in[2];
    const float* W_feat   = (const float*)d_in[3];
    const float* b_feat   = (const float*)d_in[4];
    const float* W0       = (const float*)d_in[5];
    const float* att_src0 = (const float*)d_in[6];
    const float* att_dst0 = (const float*)d_in[7];
    const float* bias0    = (const float*)d_in[8];
    const float* W1       = (const float*)d_in[9];
    const float* att_src1 = (const float*)d_in[10];
    const float* att_dst1 = (const float*)d_in[11];
    const float* bias1    = (const float*)d_in[12];
    const float* W_out    = (const float*)d_in[13];
    const float* b_out    = (const float*)d_in[14];
    float* out = (float*)d_out;

    float* agg    = (float*)d_ws;                       // NN*128 f32 (bf16 view for L0)
    float* a_srcb = agg + (size_t)NN * 128;             // NN*2
    float* a_dstb = a_srcb + (size_t)NN * 2;            // NN*2
    float* Wc     = a_dstb + (size_t)NN * 2;            // 256*128
    float* cvec   = Wc + 256 * 128;                     // 128
    unsigned short* hbuf = (unsigned short*)(cvec + 128);      // NN*128 bf16
    unsigned short* BT0hi = hbuf + (size_t)NN * 128;    // 128*320
    unsigned short* BT0lo = BT0hi + 128 * 320;
    unsigned short* BTbhi = BT0lo + 128 * 320;          // 128*128 (W0b planes)
    unsigned short* BTblo = BTbhi + 128 * 128;
    unsigned short* BT1hi = BTblo + 128 * 128;          // 128*128
    unsigned short* BT1lo = BT1hi + 128 * 128;
    unsigned short* BTohi = BT1lo + 128 * 128;          // 128*128
    unsigned short* BTolo = BTohi + 128 * 128;
    int* row_ptr = (int*)(BTolo + 128 * 128);           // NN+1
    int* colbuf  = row_ptr + NN + 1;                    // EE
    int* cnt     = colbuf + EE;                         // NPBLK*NBUCK
    int* pbase   = cnt + NPBLK * NBUCK;                 // NPBLK*NBUCK
    int* bbase   = pbase + NPBLK * NBUCK;               // NBUCK+1
    unsigned int* bbuf = (unsigned int*)agg;            // EE u32, aliases agg
    unsigned short* aggb = (unsigned short*)agg;        // bf16 view for layer0 output

    dim3 blk(256);
    const int gemmGrid = (NN + 63) / 64;
    const int nodeWaveGrid = (NN + 3) / 4;

    // ---- CSR build ----
    part_count<<<dim3(NPBLK), blk, 0, stream>>>(ei, cnt);
    part_scan<<<dim3(1), dim3(512), 0, stream>>>(cnt, pbase, bbase);
    part_scatter<<<dim3(NPBLK), blk, 0, stream>>>(ei, pbase, bbuf);
    csr_build<<<dim3(NBUCK), blk, 0, stream>>>(bbuf, bbase, row_ptr, colbuf);

    // ---- weight prep ----
    bsplit_kernel<<<dim3(1, 128), blk, 0, stream>>>(W0, 128, 40, 128, BT0hi, BT0lo, 320, 0, 64);
    bsplit_kernel<<<dim3(1, 128), blk, 0, stream>>>(W0 + 40 * 128, 128, 128, 128, BTbhi, BTblo, 128, 0, 128);
    mfma_gemm_kernel<0, 0, 0, 4><<<dim3(4), blk, 0, stream>>>(
        W_feat, 128, 128, 128, nullptr, 0, 0, 256,
        BTbhi, BTblo, 128, 128, Wc, 128, 128, nullptr,
        nullptr, nullptr, nullptr, nullptr);
    cvec_kernel<<<dim3(1), dim3(128), 0, stream>>>(b_feat, W0, cvec);
    bsplit_kernel<<<dim3(1, 128), blk, 0, stream>>>(Wc, 128, 256, 128, BT0hi, BT0lo, 320, 64, 256);
    bsplit_kernel<<<dim3(1, 128), blk, 0, stream>>>(W1, 128, 128, 128, BT1hi, BT1lo, 128, 0, 128);
    bsplit_kernel<<<dim3(1, 128), blk, 0, stream>>>(W_out, 40, 128, 40, BTohi, BTolo, 128, 0, 128);

    // ---- GAT layer 0: h0 = logits@W0a + features@Wc + cvec (attn dots fused) ----
    mfma_gemm_kernel<1, 0, 1, 4><<<dim3(gemmGrid), blk, 0, stream>>>(
        logits, 40, 40, 64, features, 256, 256, NN,
        BT0hi, BT0lo, 320, 320, hbuf, 128, 128, cvec,
        att_src0, att_dst0, a_srcb, a_dstb);
    gat_agg_fused<1, 1><<<dim3(nodeWaveGrid), blk, 0, stream>>>(
        row_ptr, colbuf, a_srcb, a_dstb, hbuf, bias0, aggb);

    // ---- GAT layer 1 (bf16 A, attn dots fused) ----
    mfma_gemm_kernel<1, 1, 1, 4><<<dim3(gemmGrid), blk, 0, stream>>>(
        aggb, 128, 128, 128, nullptr, 0, 0, NN,
        BT1hi, BT1lo, 128, 128, hbuf, 128, 128, nullptr,
        att_src1, att_dst1, a_srcb, a_dstb);
    gat_agg_fused<0, 0><<<dim3(nodeWaveGrid), blk, 0, stream>>>(
        row_ptr, colbuf, a_srcb, a_dstb, hbuf, bias1, agg);

    // ---- output projection (BN=64, 40 used) ----
    mfma_gemm_kernel<0, 0, 0, 2><<<dim3(gemmGrid), blk, 0, stream>>>(
        agg, 128, 128, 128, nullptr, 0, 0, NN,
        BTohi, BTolo, 128, 128, out, 40, 40, b_out,
        nullptr, nullptr, nullptr, nullptr);
}